// Round 3
// baseline (895.353 us; speedup 1.0000x reference)
//
#include <hip/hip_runtime.h>
#include <cstdint>
#include <cstddef>

#define WAVE 64
#define NPB 4   // waves per aggregation block

typedef short s16x8 __attribute__((ext_vector_type(8)));
typedef float f32x4 __attribute__((ext_vector_type(4)));

__device__ __forceinline__ unsigned short f2bf(float f) {
    unsigned int u = __float_as_uint(f);
    unsigned int r = (u + 0x7fffu + ((u >> 16) & 1u)) >> 16;
    return (unsigned short)r;
}
__device__ __forceinline__ float bf2f_lo(unsigned int v) { return __uint_as_float(v << 16); }
__device__ __forceinline__ float bf2f_hi(unsigned int v) { return __uint_as_float(v & 0xffff0000u); }
__device__ __forceinline__ float lrelu02(float e) { return (e > 0.f) ? e : 0.2f * e; }

// ---------------- fused CSR construction (mol + pro in one index space) ----------------
// node ids: mol [0, N_MOL), pro [N_MOL, N_MOL+N_PRO)
// edge positions: mol [0, E_MOL), pro [E_MOL, E_MOL+E_PRO)

__global__ __launch_bounds__(256) void k_count_all(const int* __restrict__ mol_dst,
                                                   const int* __restrict__ pro_dst,
                                                   int* __restrict__ cnt, int N_MOL, int E_MOL, int ET) {
    int i0 = blockIdx.x * 1024 + threadIdx.x;
#pragma unroll
    for (int k = 0; k < 4; k++) {
        int e = i0 + k * 256;
        if (e < ET) {
            int d = (e < E_MOL) ? mol_dst[e] : (N_MOL + pro_dst[e - E_MOL]);
            atomicAdd(&cnt[d], 1);
        }
    }
}

__global__ __launch_bounds__(256) void k_scan1(const int* __restrict__ cnt, int* __restrict__ incl,
                                               int* __restrict__ bsums, int n) {
    __shared__ int sm[256];
    int i = blockIdx.x * 256 + threadIdx.x;
    int v = (i < n) ? cnt[i] : 0;
    sm[threadIdx.x] = v;
    __syncthreads();
    for (int off = 1; off < 256; off <<= 1) {
        int t = (threadIdx.x >= off) ? sm[threadIdx.x - off] : 0;
        __syncthreads();
        sm[threadIdx.x] += t;
        __syncthreads();
    }
    if (i < n) incl[i] = sm[threadIdx.x];
    if (threadIdx.x == 255) bsums[blockIdx.x] = sm[255];
}

__global__ __launch_bounds__(1024) void k_scan2(int* __restrict__ bsums, int nb) {
    __shared__ int sm[1024];
    int v = (threadIdx.x < nb) ? bsums[threadIdx.x] : 0;
    sm[threadIdx.x] = v;
    __syncthreads();
    for (int off = 1; off < 1024; off <<= 1) {
        int t = (threadIdx.x >= off) ? sm[threadIdx.x - off] : 0;
        __syncthreads();
        sm[threadIdx.x] += t;
        __syncthreads();
    }
    if (threadIdx.x < nb) bsums[threadIdx.x] = sm[threadIdx.x] - v;  // exclusive
}

__global__ __launch_bounds__(256) void k_scan3_all(const int* __restrict__ incl, const int* __restrict__ cnt,
                                                   const int* __restrict__ boff,
                                                   int* __restrict__ mol_rowp, int* __restrict__ pro_rowp,
                                                   int* __restrict__ cur,
                                                   int N_MOL, int N_PRO, int E_MOL, int E_PRO) {
    int i = blockIdx.x * 256 + threadIdx.x;
    int NT = N_MOL + N_PRO;
    if (i < NT) {
        int ex = incl[i] - cnt[i] + boff[blockIdx.x];
        cur[i] = ex;
        if (i < N_MOL) mol_rowp[i] = ex;
        else pro_rowp[i - N_MOL] = ex - E_MOL;  // pro rowp is local
    }
    if (i == 0) {
        mol_rowp[N_MOL] = E_MOL;
        pro_rowp[N_PRO] = E_PRO;
    }
}

__global__ __launch_bounds__(256) void k_scatter_all(const int* __restrict__ mol_src, const int* __restrict__ mol_dst,
                                                     const int* __restrict__ pro_src, const int* __restrict__ pro_dst,
                                                     const float* __restrict__ pro_w, int* __restrict__ cur,
                                                     int* __restrict__ csrc, float* __restrict__ cw,
                                                     int N_MOL, int E_MOL, int ET) {
    int i0 = blockIdx.x * 1024 + threadIdx.x;
#pragma unroll
    for (int k = 0; k < 4; k++) {
        int e = i0 + k * 256;
        if (e < ET) {
            int s, d;
            float w = 0.f;
            bool isp = (e >= E_MOL);
            if (isp) {
                int ep = e - E_MOL;
                s = pro_src[ep];
                d = N_MOL + pro_dst[ep];
                w = pro_w[ep];
            } else {
                s = mol_src[e];
                d = mol_dst[e];
            }
            int pos = atomicAdd(&cur[d], 1);
            csrc[pos] = s;  // local source node id
            if (isp) cw[pos] = w;
        }
    }
}

// node-parallel degree + dinv (no atomics; rowp/cw are pro-local)
__global__ __launch_bounds__(256) void k_deg_dinv(const int* __restrict__ rowp, const float* __restrict__ cw,
                                                  float* __restrict__ dinv, float* __restrict__ dinv2, int N) {
    int n = blockIdx.x * 256 + threadIdx.x;
    if (n < N) {
        int b = rowp[n], e = rowp[n + 1];
        float s = 0.f;
        for (int p = b; p < e; p++) s += cw[p];
        float di = rsqrtf(s + 1.0f);
        dinv[n] = di;
        dinv2[n] = di * di;
    }
}

// ---------------- edge-weight precompute (node-parallel, wave per dst node) ----------------

template <int H>
__global__ __launch_bounds__(NPB * 64) void k_edge_gat_n(const int* __restrict__ rowp, const int* __restrict__ cidx,
                                                         const float* __restrict__ as_, const float* __restrict__ ad_,
                                                         float* __restrict__ ew, int N) {
    int n = blockIdx.x * NPB + (threadIdx.x >> 6);
    if (n >= N) return;
    int lane = threadIdx.x & 63;
    float adn[H], msub[H];
#pragma unroll
    for (int h = 0; h < H; h++) {
        adn[h] = ad_[(size_t)n * H + h];
        msub[h] = lrelu02(as_[(size_t)n * H + h] + adn[h]);
    }
    int beg = rowp[n], end = rowp[n + 1];
    for (int base = beg; base < end; base += WAVE) {
        int cnt = end - base;
        if (cnt > WAVE) cnt = WAVE;
        if (lane < cnt) {
            int s = cidx[base + lane];
            if (H == 2) {
                float2 o;
                o.x = __expf(lrelu02(as_[(size_t)s * 2 + 0] + adn[0]) - msub[0]);
                o.y = __expf(lrelu02(as_[(size_t)s * 2 + 1] + adn[1]) - msub[1]);
                *(float2*)(ew + (size_t)(base + lane) * 2) = o;
            } else {
                ew[base + lane] = __expf(lrelu02(as_[s] + adn[0]) - msub[0]);
            }
        }
    }
}

__global__ __launch_bounds__(NPB * 64) void k_edge_gcn_n(const int* __restrict__ rowp, const int* __restrict__ cidx,
                                                         const float* __restrict__ cw, const float* __restrict__ dinv,
                                                         float* __restrict__ ew, int N) {
    int n = blockIdx.x * NPB + (threadIdx.x >> 6);
    if (n >= N) return;
    int lane = threadIdx.x & 63;
    float di = dinv[n];
    int beg = rowp[n], end = rowp[n + 1];
    for (int base = beg; base < end; base += WAVE) {
        int cnt = end - base;
        if (cnt > WAVE) cnt = WAVE;
        if (lane < cnt) {
            int s = cidx[base + lane];
            ew[base + lane] = dinv[s] * cw[base + lane] * di;
        }
    }
}

// ---------------- conversions ----------------

__global__ __launch_bounds__(256) void k_cvt_x(const float* __restrict__ in, unsigned short* __restrict__ out,
                                               int K, int Kp, long long total) {
    long long idx = (long long)blockIdx.x * 256 + threadIdx.x;
    if (idx < total) {
        int n = (int)(idx / Kp);
        int k = (int)(idx - (long long)n * Kp);
        out[idx] = (k < K) ? f2bf(in[(long long)n * K + k]) : (unsigned short)0;
    }
}

__global__ __launch_bounds__(256) void k_cvt_w(const float* __restrict__ W, unsigned short* __restrict__ WT,
                                               int K, int M, int Kp) {
    int idx = blockIdx.x * 256 + threadIdx.x;
    if (idx < M * Kp) {
        int m = idx / Kp;
        int k = idx - m * Kp;
        WT[idx] = (k < K) ? f2bf(W[(long long)k * M + m]) : (unsigned short)0;
    }
}

__global__ __launch_bounds__(64) void k_prep_va(const float* __restrict__ W,
                                                const float* __restrict__ a_src, const float* __restrict__ a_dst,
                                                unsigned short* __restrict__ WT,
                                                int K, int M, int C, int Kp, int H) {
    int b = blockIdx.x;          // [0, 2*H*Kp)
    int k = b % Kp;
    int th = b / Kp;             // t*H + h
    int t = th / H;
    int h = th - t * H;
    size_t orow = (size_t)(M + t * H + h) * Kp;
    int lane = threadIdx.x;
    if (k >= K) {
        if (lane == 0) WT[orow + k] = 0;
        return;
    }
    const float* a = t ? a_dst : a_src;
    int hoff = h * C;
    const float* wrow = W + (size_t)k * M + hoff;
    float acc = 0.f;
    for (int c = lane; c < C; c += 64) acc += wrow[c] * a[hoff + c];
    for (int off = 32; off > 0; off >>= 1) acc += __shfl_down(acc, off);
    if (lane == 0) WT[orow + k] = f2bf(acc);
}

// ---------------- bf16 MFMA GEMM + alpha epilogue ----------------

#define TBM 128
#define TBN 128
#define TBK 32
#define LDK 40

__global__ __launch_bounds__(256) void k_mfma_gemm(const unsigned short* __restrict__ A,
                                                   const unsigned short* __restrict__ BT,
                                                   unsigned short* __restrict__ Cbf,
                                                   float* __restrict__ asb, float* __restrict__ adb,
                                                   int N, int Kp, int M, int Mext, int Mp, int H) {
    __shared__ __align__(16) unsigned short As[TBM * LDK];
    __shared__ __align__(16) unsigned short Bs[TBN * LDK];
    int tid = threadIdx.x;
    int wave = tid >> 6;
    int lane = tid & 63;
    int rowBase = blockIdx.y * TBM;
    int colBase = blockIdx.x * TBN;
    int wm = (wave & 1) * 64;
    int wn = (wave >> 1) * 64;
    int l15 = lane & 15;
    int quad = lane >> 4;

    f32x4 acc[4][4];
    f32x4 z4 = {0.f, 0.f, 0.f, 0.f};
#pragma unroll
    for (int i = 0; i < 4; i++)
#pragma unroll
        for (int j = 0; j < 4; j++) acc[i][j] = z4;

    int srow = tid >> 2;
    int skg = tid & 3;
    const uint4 zero16 = {0u, 0u, 0u, 0u};

    for (int k0 = 0; k0 < Kp; k0 += TBK) {
#pragma unroll
        for (int half = 0; half < 2; half++) {
            int row = srow + half * 64;
            int gk = k0 + skg * 8;
            bool kok = (gk < Kp);
            {
                int gr = rowBase + row;
                uint4 v = zero16;
                if (kok && gr < N) v = *(const uint4*)(A + (size_t)gr * Kp + gk);
                *(uint4*)(As + row * LDK + skg * 8) = v;
            }
            {
                int gc = colBase + row;
                uint4 v = zero16;
                if (kok && gc < Mext) v = *(const uint4*)(BT + (size_t)gc * Kp + gk);
                *(uint4*)(Bs + row * LDK + skg * 8) = v;
            }
        }
        __syncthreads();

        s16x8 af[4], bfr[4];
#pragma unroll
        for (int mt = 0; mt < 4; mt++)
            af[mt] = *(const s16x8*)(As + (wm + mt * 16 + l15) * LDK + quad * 8);
#pragma unroll
        for (int nt = 0; nt < 4; nt++)
            bfr[nt] = *(const s16x8*)(Bs + (wn + nt * 16 + l15) * LDK + quad * 8);
#pragma unroll
        for (int mt = 0; mt < 4; mt++)
#pragma unroll
            for (int nt = 0; nt < 4; nt++)
                acc[mt][nt] = __builtin_amdgcn_mfma_f32_16x16x32_bf16(af[mt], bfr[nt], acc[mt][nt], 0, 0, 0);
        __syncthreads();
    }

#pragma unroll
    for (int mt = 0; mt < 4; mt++) {
#pragma unroll
        for (int r = 0; r < 4; r++) {
            int row = rowBase + wm + mt * 16 + quad * 4 + r;
            if (row < N) {
#pragma unroll
                for (int nt = 0; nt < 4; nt++) {
                    int col = colBase + wn + nt * 16 + l15;
                    float v = acc[mt][nt][r];
                    if (col < M) {
                        Cbf[(size_t)row * Mp + col] = f2bf(v);
                    } else if (asb != nullptr && col < M + 2 * H) {
                        int t = col - M;
                        if (t < H) asb[(size_t)row * H + t] = v;
                        else adb[(size_t)row * H + (t - H)] = v;
                    }
                }
            }
        }
    }
}

// ---------------- packed aggregation: G edges per wave, dwordx4 gathers ----------------
// Lane layout: lane = g*SLOTS + slot. Full feature row = PARTS*SLOTS uint4s (8 bf16 each);
// each (node, part) pair is one wave handling SLOTS slots. One gather instruction covers
// G edges. Edge weights precomputed (ew). Cross-group reduce via ds_bpermute at the end.

template <int SLOTS, int G, int H, bool SM, int PARTS>
__global__ __launch_bounds__(NPB * 64) void k_agg4(const unsigned short* __restrict__ hfeat,
                                                   const float* __restrict__ ew,
                                                   const float* __restrict__ selfw,  // used when !SM
                                                   const int* __restrict__ rowp, const int* __restrict__ cidx,
                                                   const float* __restrict__ bias,
                                                   float* __restrict__ out_f,
                                                   unsigned short* __restrict__ out_bf,
                                                   int HC, int ldo, int relu, int N) {
    int item = blockIdx.x * NPB + (threadIdx.x >> 6);
    if (item >= N * PARTS) return;
    int n = item / PARTS;
    int part = item - n * PARTS;
    int lane = threadIdx.x & 63;
    constexpr int ROWB = SLOTS * PARTS * 16;  // full row bytes
    int g = lane / SLOTS;
    int slot = lane - g * SLOTS;
    int slotg = part * SLOTS + slot;
    bool act = (g < G);
    int ch0 = slotg * 8;
    int C = HC / H;
    int beg = rowp[n], end = rowp[n + 1];

    bool h1q[4];
#pragma unroll
    for (int q = 0; q < 4; q++) h1q[q] = (H == 2) && ((ch0 + 2 * q) >= C);

    float sw = SM ? 1.f : selfw[n];
    float accx[4], accy[4];
#pragma unroll
    for (int q = 0; q < 4; q++) { accx[q] = 0.f; accy[q] = 0.f; }
    if (act && g == 0) {
        uint4 v = *(const uint4*)((const char*)hfeat + (size_t)n * ROWB + slotg * 16);
        unsigned int vv[4] = {v.x, v.y, v.z, v.w};
#pragma unroll
        for (int q = 0; q < 4; q++) { accx[q] = sw * bf2f_lo(vv[q]); accy[q] = sw * bf2f_hi(vv[q]); }
    }

    float wsum[H];
#pragma unroll
    for (int h = 0; h < H; h++) wsum[h] = 0.f;

    for (int base = beg; base < end; base += WAVE) {
        int cnt = end - base;
        if (cnt > WAVE) cnt = WAVE;
        int s_l = 0;
        float w_l[H];
#pragma unroll
        for (int h = 0; h < H; h++) w_l[h] = 0.f;
        if (lane < cnt) {
            s_l = cidx[base + lane];
            if (H == 2) {
                float2 t = *(const float2*)(ew + (size_t)(base + lane) * 2);
                w_l[0] = t.x;
                w_l[1] = t.y;
                if (SM) { wsum[0] += t.x; wsum[1] += t.y; }
            } else {
                w_l[0] = ew[base + lane];
                if (SM) wsum[0] += w_l[0];
            }
        }
        for (int j0 = 0; j0 < cnt; j0 += 2 * G) {
            // group A
            int sA;
            float wA[H];
            uint4 vA;
            {
                int jj = j0 + g;
                bool pad = (jj >= cnt);
                if (jj > cnt - 1) jj = cnt - 1;
                int ba = jj << 2;
                sA = __builtin_amdgcn_ds_bpermute(ba, s_l);
#pragma unroll
                for (int h = 0; h < H; h++) {
                    float t = __uint_as_float(
                        (unsigned)__builtin_amdgcn_ds_bpermute(ba, (int)__float_as_uint(w_l[h])));
                    wA[h] = pad ? 0.f : t;
                }
                if (act) {
                    unsigned voff = (unsigned)sA * ROWB + slotg * 16;
                    vA = *(const uint4*)((const char*)hfeat + voff);
                }
            }
            // group B (uniform predicate)
            bool haveB = (j0 + G < cnt);
            int sB;
            float wB[H];
            uint4 vB;
            if (haveB) {
                int jj = j0 + G + g;
                bool pad = (jj >= cnt);
                if (jj > cnt - 1) jj = cnt - 1;
                int ba = jj << 2;
                sB = __builtin_amdgcn_ds_bpermute(ba, s_l);
#pragma unroll
                for (int h = 0; h < H; h++) {
                    float t = __uint_as_float(
                        (unsigned)__builtin_amdgcn_ds_bpermute(ba, (int)__float_as_uint(w_l[h])));
                    wB[h] = pad ? 0.f : t;
                }
                if (act) {
                    unsigned voff = (unsigned)sB * ROWB + slotg * 16;
                    vB = *(const uint4*)((const char*)hfeat + voff);
                }
            }
            if (act) {
                unsigned int va[4] = {vA.x, vA.y, vA.z, vA.w};
#pragma unroll
                for (int q = 0; q < 4; q++) {
                    float wq = (H == 2) ? (h1q[q] ? wA[1] : wA[0]) : wA[0];
                    accx[q] += wq * bf2f_lo(va[q]);
                    accy[q] += wq * bf2f_hi(va[q]);
                }
                if (haveB) {
                    unsigned int ub[4] = {vB.x, vB.y, vB.z, vB.w};
#pragma unroll
                    for (int q = 0; q < 4; q++) {
                        float wq = (H == 2) ? (h1q[q] ? wB[1] : wB[0]) : wB[0];
                        accx[q] += wq * bf2f_lo(ub[q]);
                        accy[q] += wq * bf2f_hi(ub[q]);
                    }
                }
            }
        }
    }

    // cross-group channel reduction into lanes [0, SLOTS)
    if (G == 3) {
#pragma unroll
        for (int q = 0; q < 4; q++) {
            int b1a = (lane + SLOTS) << 2, b2a = (lane + 2 * SLOTS) << 2;
            float t1 = __uint_as_float((unsigned)__builtin_amdgcn_ds_bpermute(b1a, (int)__float_as_uint(accx[q])));
            float t2 = __uint_as_float((unsigned)__builtin_amdgcn_ds_bpermute(b2a, (int)__float_as_uint(accx[q])));
            accx[q] += t1 + t2;
            float t3 = __uint_as_float((unsigned)__builtin_amdgcn_ds_bpermute(b1a, (int)__float_as_uint(accy[q])));
            float t4 = __uint_as_float((unsigned)__builtin_amdgcn_ds_bpermute(b2a, (int)__float_as_uint(accy[q])));
            accy[q] += t3 + t4;
        }
    } else if (G == 8) {
#pragma unroll
        for (int st = 4; st >= 1; st >>= 1) {
            int ba = (lane + st * SLOTS) << 2;
#pragma unroll
            for (int q = 0; q < 4; q++) {
                accx[q] += __uint_as_float((unsigned)__builtin_amdgcn_ds_bpermute(ba, (int)__float_as_uint(accx[q])));
                accy[q] += __uint_as_float((unsigned)__builtin_amdgcn_ds_bpermute(ba, (int)__float_as_uint(accy[q])));
            }
        }
    }

    float rs[H];
    if (SM) {
#pragma unroll
        for (int h = 0; h < H; h++) {
            float t = wsum[h];
            for (int off = 32; off > 0; off >>= 1) t += __shfl_xor(t, off);
            rs[h] = 1.f / (1.f + t + 1e-16f);  // +1 = self term
        }
    } else {
#pragma unroll
        for (int h = 0; h < H; h++) rs[h] = 1.f;
    }

    if (lane < SLOTS) {
        float o[8];
#pragma unroll
        for (int q = 0; q < 4; q++) {
            float r = (H == 2) ? (h1q[q] ? rs[1] : rs[0]) : rs[0];
            int c0 = ch0 + 2 * q;
            float b0 = (c0 < HC) ? bias[c0] : 0.f;
            float b1v = (c0 + 1 < HC) ? bias[c0 + 1] : 0.f;
            float o0 = accx[q] * r + b0;
            float o1 = accy[q] * r + b1v;
            if (relu) { o0 = fmaxf(o0, 0.f); o1 = fmaxf(o1, 0.f); }
            if (c0 >= HC) o0 = 0.f;
            if (c0 + 1 >= HC) o1 = 0.f;
            o[2 * q] = o0;
            o[2 * q + 1] = o1;
        }
        if (out_bf) {
            uint4 pk;
            unsigned* pp = (unsigned*)&pk;
#pragma unroll
            for (int q = 0; q < 4; q++)
                pp[q] = (unsigned)f2bf(o[2 * q]) | ((unsigned)f2bf(o[2 * q + 1]) << 16);
            *(uint4*)((char*)out_bf + (size_t)n * ((size_t)ldo * 2) + slotg * 16) = pk;
        } else {
#pragma unroll
            for (int half = 0; half < 2; half++) {
                int c0 = ch0 + half * 4;
                if (c0 < HC) {
                    float4 f4 = make_float4(o[half * 4], o[half * 4 + 1], o[half * 4 + 2], o[half * 4 + 3]);
                    *(float4*)(out_f + (size_t)n * HC + c0) = f4;
                }
            }
        }
    }
}

// ---------------- launch ----------------

extern "C" void kernel_launch(void* const* d_in, const int* in_sizes, int n_in,
                              void* d_out, int out_size, void* d_ws, size_t ws_size,
                              hipStream_t stream) {
    const int N_MOL = in_sizes[0] / 78;
    const int E_MOL = in_sizes[1] / 2;
    const int N_PRO = in_sizes[2] / 33;
    const int E_PRO = in_sizes[3] / 2;
    const int NT = N_MOL + N_PRO;
    const int ET = E_MOL + E_PRO;

    const float* mol_x = (const float*)d_in[0];
    const int* mol_ei = (const int*)d_in[1];
    const float* pro_x = (const float*)d_in[2];
    const int* pro_ei = (const int*)d_in[3];
    const float* pro_ew = (const float*)d_in[4];
    const float *W1 = (const float*)d_in[5], *as1 = (const float*)d_in[6], *ad1 = (const float*)d_in[7],
                *b1 = (const float*)d_in[8];
    const float *W2 = (const float*)d_in[9], *as2 = (const float*)d_in[10], *ad2 = (const float*)d_in[11],
                *b2 = (const float*)d_in[12];
    const float *W3 = (const float*)d_in[13], *as3 = (const float*)d_in[14], *ad3 = (const float*)d_in[15],
                *b3 = (const float*)d_in[16];
    const float *Wp1 = (const float*)d_in[17], *bp1 = (const float*)d_in[18];
    const float *Wp2 = (const float*)d_in[19], *aps2 = (const float*)d_in[20], *apd2 = (const float*)d_in[21],
                *bp2 = (const float*)d_in[22];
    const float *Wp3 = (const float*)d_in[23], *aps3 = (const float*)d_in[24], *apd3 = (const float*)d_in[25],
                *bp3 = (const float*)d_in[26];

    float* out_mol = (float*)d_out;
    float* out_pro = (float*)d_out + (size_t)N_MOL * 312;

    char* p = (char*)d_ws;
    auto alloc = [&](size_t bytes) -> void* {
        void* r = (void*)p;
        p += (bytes + 255) & ~(size_t)255;
        return r;
    };
    int* cnt_all  = (int*)alloc((size_t)NT * 4);
    int* incl     = (int*)alloc((size_t)NT * 4);
    int* cur_all  = (int*)alloc((size_t)NT * 4);
    int* bsums    = (int*)alloc(1024 * 4);
    int* mol_rowp = (int*)alloc((size_t)(N_MOL + 1) * 4);
    int* pro_rowp = (int*)alloc((size_t)(N_PRO + 1) * 4);
    int* csrc_all = (int*)alloc((size_t)ET * 4);
    float* cw_all = (float*)alloc((size_t)ET * 4);
    float* dinv   = (float*)alloc((size_t)N_PRO * 4);
    float* dinv2  = (float*)alloc((size_t)N_PRO * 4);
    float* asb = (float*)alloc((size_t)N_PRO * 2 * 4);
    float* adb = (float*)alloc((size_t)N_PRO * 2 * 4);
    float* ewb = (float*)alloc((size_t)E_PRO * 2 * 4);  // edge weights (reused sequentially)
    unsigned short* hb = (unsigned short*)alloc((size_t)N_MOL * 320 * 2);
    unsigned short* xb = (unsigned short*)alloc((size_t)N_MOL * 320 * 2);
    unsigned short* wt1 = (unsigned short*)alloc((size_t)160 * 80 * 2);
    unsigned short* wt2 = (unsigned short*)alloc((size_t)320 * 160 * 2);
    unsigned short* wt3 = (unsigned short*)alloc((size_t)320 * 320 * 2);
    unsigned short* wtp1 = (unsigned short*)alloc((size_t)40 * 40 * 2);
    unsigned short* wtp2 = (unsigned short*)alloc((size_t)136 * 40 * 2);
    unsigned short* wtp3 = (unsigned short*)alloc((size_t)136 * 136 * 2);
    (void)ws_size;

    int* mol_csrc = csrc_all;            // mol edges at [0, E_MOL)
    int* pro_csrc = csrc_all + E_MOL;    // pro edges at [E_MOL, ET), local pointers
    float* pro_cw = cw_all + E_MOL;

    const int* mol_src = mol_ei;
    const int* mol_dst = mol_ei + E_MOL;
    const int* pro_src = pro_ei;
    const int* pro_dst = pro_ei + E_PRO;

    // ---- fused CSR build ----
    hipMemsetAsync(cnt_all, 0, (size_t)NT * 4, stream);
    k_count_all<<<(ET + 1023) / 1024, 256, 0, stream>>>(mol_dst, pro_dst, cnt_all, N_MOL, E_MOL, ET);
    int nbT = (NT + 255) / 256;
    k_scan1<<<nbT, 256, 0, stream>>>(cnt_all, incl, bsums, NT);
    k_scan2<<<1, 1024, 0, stream>>>(bsums, nbT);
    k_scan3_all<<<nbT, 256, 0, stream>>>(incl, cnt_all, bsums, mol_rowp, pro_rowp, cur_all,
                                         N_MOL, N_PRO, E_MOL, E_PRO);
    k_scatter_all<<<(ET + 1023) / 1024, 256, 0, stream>>>(mol_src, mol_dst, pro_src, pro_dst, pro_ew,
                                                          cur_all, csrc_all, cw_all, N_MOL, E_MOL, ET);
    k_deg_dinv<<<(N_PRO + 255) / 256, 256, 0, stream>>>(pro_rowp, pro_cw, dinv, dinv2, N_PRO);

    // ---- weight converts + fused alpha-vector rows ----
    auto cvtw = [&](const float* W, unsigned short* WT, int K, int M, int Kp) {
        k_cvt_w<<<(M * Kp + 255) / 256, 256, 0, stream>>>(W, WT, K, M, Kp);
    };
    cvtw(W1, wt1, 78, 156, 80);
    cvtw(W2, wt2, 156, 312, 160);
    cvtw(W3, wt3, 312, 312, 320);
    cvtw(Wp1, wtp1, 33, 33, 40);
    cvtw(Wp2, wtp2, 33, 132, 40);
    cvtw(Wp3, wtp3, 132, 132, 136);
    k_prep_va<<<2 * 2 * 80, 64, 0, stream>>>(W1, as1, ad1, wt1, 78, 156, 78, 80, 2);
    k_prep_va<<<2 * 2 * 160, 64, 0, stream>>>(W2, as2, ad2, wt2, 156, 312, 156, 160, 2);
    k_prep_va<<<2 * 1 * 320, 64, 0, stream>>>(W3, as3, ad3, wt3, 312, 312, 312, 320, 1);
    k_prep_va<<<2 * 2 * 40, 64, 0, stream>>>(Wp2, aps2, apd2, wtp2, 33, 132, 66, 40, 2);
    k_prep_va<<<2 * 1 * 136, 64, 0, stream>>>(Wp3, aps3, apd3, wtp3, 132, 132, 132, 136, 1);

    auto gemm = [&](const unsigned short* A, const unsigned short* BT, unsigned short* C,
                    float* as_o, float* ad_o, int N, int Kp, int M, int Mp, int H) {
        int Mext = (as_o != nullptr) ? (M + 2 * H) : M;
        dim3 grid((Mext + TBN - 1) / TBN, (N + TBM - 1) / TBM);
        k_mfma_gemm<<<grid, 256, 0, stream>>>(A, BT, C, as_o, ad_o, N, Kp, M, Mext, Mp, H);
    };

    auto waves = [](int items) { return dim3((items + NPB - 1) / NPB); };

    // ---- mol branch ----
    {
        long long tot = (long long)N_MOL * 80;
        k_cvt_x<<<(int)((tot + 255) / 256), 256, 0, stream>>>(mol_x, xb, 78, 80, tot);
    }
    // conv1: GAT 78 -> 78, H=2 (HC=156, row 160 = 20 slots), relu
    gemm(xb, wt1, hb, asb, adb, N_MOL, 80, 156, 160, 2);
    k_edge_gat_n<2><<<waves(N_MOL), NPB * 64, 0, stream>>>(mol_rowp, mol_csrc, asb, adb, ewb, N_MOL);
    k_agg4<20, 3, 2, true, 1><<<waves(N_MOL), NPB * 64, 0, stream>>>(hb, ewb, nullptr, mol_rowp, mol_csrc, b1,
                                                                     nullptr, xb, 156, 160, 1, N_MOL);
    // conv2: GAT 156 -> 156, H=2 (HC=312, row 320 = 2 parts x 20 slots), relu
    gemm(xb, wt2, hb, asb, adb, N_MOL, 160, 312, 320, 2);
    k_edge_gat_n<2><<<waves(N_MOL), NPB * 64, 0, stream>>>(mol_rowp, mol_csrc, asb, adb, ewb, N_MOL);
    k_agg4<20, 3, 2, true, 2><<<waves(N_MOL * 2), NPB * 64, 0, stream>>>(hb, ewb, nullptr, mol_rowp, mol_csrc, b2,
                                                                         nullptr, xb, 312, 320, 1, N_MOL);
    // conv3: GAT 312 -> 312, H=1, no relu -> fp32 out
    gemm(xb, wt3, hb, asb, adb, N_MOL, 320, 312, 320, 1);
    k_edge_gat_n<1><<<waves(N_MOL), NPB * 64, 0, stream>>>(mol_rowp, mol_csrc, asb, adb, ewb, N_MOL);
    k_agg4<20, 3, 1, true, 2><<<waves(N_MOL * 2), NPB * 64, 0, stream>>>(hb, ewb, nullptr, mol_rowp, mol_csrc, b3,
                                                                         out_mol, nullptr, 312, 320, 0, N_MOL);

    // ---- pro branch ----
    {
        long long tot = (long long)N_PRO * 40;
        k_cvt_x<<<(int)((tot + 255) / 256), 256, 0, stream>>>(pro_x, xb, 33, 40, tot);
    }
    // gcn: 33 -> 33 (row 40 = 5 slots, G=8), relu
    gemm(xb, wtp1, hb, nullptr, nullptr, N_PRO, 40, 33, 40, 0);
    k_edge_gcn_n<<<waves(N_PRO), NPB * 64, 0, stream>>>(pro_rowp, pro_csrc, pro_cw, dinv, ewb, N_PRO);
    k_agg4<5, 8, 1, false, 1><<<waves(N_PRO), NPB * 64, 0, stream>>>(hb, ewb, dinv2, pro_rowp, pro_csrc, bp1,
                                                                     nullptr, xb, 33, 40, 1, N_PRO);
    // conv2: GAT 33 -> 66, H=2 (HC=132, row 136 = 17 slots), relu
    gemm(xb, wtp2, hb, asb, adb, N_PRO, 40, 132, 136, 2);
    k_edge_gat_n<2><<<waves(N_PRO), NPB * 64, 0, stream>>>(pro_rowp, pro_csrc, asb, adb, ewb, N_PRO);
    k_agg4<17, 3, 2, true, 1><<<waves(N_PRO), NPB * 64, 0, stream>>>(hb, ewb, nullptr, pro_rowp, pro_csrc, bp2,
                                                                     nullptr, xb, 132, 136, 1, N_PRO);
    // conv3: GAT 132 -> 132, H=1, relu -> fp32 out
    gemm(xb, wtp3, hb, asb, adb, N_PRO, 136, 132, 136, 1);
    k_edge_gat_n<1><<<waves(N_PRO), NPB * 64, 0, stream>>>(pro_rowp, pro_csrc, asb, adb, ewb, N_PRO);
    k_agg4<17, 3, 1, true, 1><<<waves(N_PRO), NPB * 64, 0, stream>>>(hb, ewb, nullptr, pro_rowp, pro_csrc, bp3,
                                                                     out_pro, nullptr, 132, 136, 1, N_PRO);
}

// Round 4
// 870.108 us; speedup vs baseline: 1.0290x; 1.0290x over previous
//
#include <hip/hip_runtime.h>
#include <cstdint>
#include <cstddef>

#define WAVE 64
#define NPB 4   // waves per aggregation block

typedef short s16x8 __attribute__((ext_vector_type(8)));
typedef float f32x4 __attribute__((ext_vector_type(4)));

__device__ __forceinline__ unsigned short f2bf(float f) {
    unsigned int u = __float_as_uint(f);
    unsigned int r = (u + 0x7fffu + ((u >> 16) & 1u)) >> 16;
    return (unsigned short)r;
}
__device__ __forceinline__ float bf2f_lo(unsigned int v) { return __uint_as_float(v << 16); }
__device__ __forceinline__ float bf2f_hi(unsigned int v) { return __uint_as_float(v & 0xffff0000u); }
__device__ __forceinline__ float lrelu02(float e) { return (e > 0.f) ? e : 0.2f * e; }

// ---------------- fused CSR construction (mol + pro in one index space) ----------------
// node ids: mol [0, N_MOL), pro [N_MOL, N_MOL+N_PRO)
// edge positions: mol [0, E_MOL), pro [E_MOL, E_MOL+E_PRO)

__global__ __launch_bounds__(256) void k_count_all(const int* __restrict__ mol_dst,
                                                   const int* __restrict__ pro_dst,
                                                   int* __restrict__ cnt, int N_MOL, int E_MOL, int ET) {
    int i0 = blockIdx.x * 1024 + threadIdx.x;
#pragma unroll
    for (int k = 0; k < 4; k++) {
        int e = i0 + k * 256;
        if (e < ET) {
            int d = (e < E_MOL) ? mol_dst[e] : (N_MOL + pro_dst[e - E_MOL]);
            atomicAdd(&cnt[d], 1);
        }
    }
}

__global__ __launch_bounds__(256) void k_scan1(const int* __restrict__ cnt, int* __restrict__ incl,
                                               int* __restrict__ bsums, int n) {
    __shared__ int sm[256];
    int i = blockIdx.x * 256 + threadIdx.x;
    int v = (i < n) ? cnt[i] : 0;
    sm[threadIdx.x] = v;
    __syncthreads();
    for (int off = 1; off < 256; off <<= 1) {
        int t = (threadIdx.x >= off) ? sm[threadIdx.x - off] : 0;
        __syncthreads();
        sm[threadIdx.x] += t;
        __syncthreads();
    }
    if (i < n) incl[i] = sm[threadIdx.x];
    if (threadIdx.x == 255) bsums[blockIdx.x] = sm[255];
}

__global__ __launch_bounds__(1024) void k_scan2(int* __restrict__ bsums, int nb) {
    __shared__ int sm[1024];
    int v = (threadIdx.x < nb) ? bsums[threadIdx.x] : 0;
    sm[threadIdx.x] = v;
    __syncthreads();
    for (int off = 1; off < 1024; off <<= 1) {
        int t = (threadIdx.x >= off) ? sm[threadIdx.x - off] : 0;
        __syncthreads();
        sm[threadIdx.x] += t;
        __syncthreads();
    }
    if (threadIdx.x < nb) bsums[threadIdx.x] = sm[threadIdx.x] - v;  // exclusive
}

__global__ __launch_bounds__(256) void k_scan3_all(const int* __restrict__ incl, const int* __restrict__ cnt,
                                                   const int* __restrict__ boff,
                                                   int* __restrict__ mol_rowp, int* __restrict__ pro_rowp,
                                                   int* __restrict__ cur,
                                                   int N_MOL, int N_PRO, int E_MOL, int E_PRO) {
    int i = blockIdx.x * 256 + threadIdx.x;
    int NT = N_MOL + N_PRO;
    if (i < NT) {
        int ex = incl[i] - cnt[i] + boff[blockIdx.x];
        cur[i] = ex;
        if (i < N_MOL) mol_rowp[i] = ex;
        else pro_rowp[i - N_MOL] = ex - E_MOL;  // pro rowp is local
    }
    if (i == 0) {
        mol_rowp[N_MOL] = E_MOL;
        pro_rowp[N_PRO] = E_PRO;
    }
}

// scatter: one int2 {src, w-bits} per edge -> one dirty cache line per edge
__global__ __launch_bounds__(256) void k_scatter_all(const int* __restrict__ mol_src, const int* __restrict__ mol_dst,
                                                     const int* __restrict__ pro_src, const int* __restrict__ pro_dst,
                                                     const float* __restrict__ pro_w, int* __restrict__ cur,
                                                     int2* __restrict__ cpack, int N_MOL, int E_MOL, int ET) {
    int e = blockIdx.x * 256 + threadIdx.x;
    if (e < ET) {
        int s, d;
        int wbits = 0;
        if (e >= E_MOL) {
            int ep = e - E_MOL;
            s = pro_src[ep];
            d = N_MOL + pro_dst[ep];
            wbits = __float_as_int(pro_w[ep]);
        } else {
            s = mol_src[e];
            d = mol_dst[e];
        }
        int pos = atomicAdd(&cur[d], 1);
        int2 pk;
        pk.x = s;
        pk.y = wbits;
        cpack[pos] = pk;
    }
}

// node-parallel degree + dinv (no atomics; rowp/cpack are pro-local)
__global__ __launch_bounds__(256) void k_deg_dinv(const int* __restrict__ rowp, const int2* __restrict__ cpack,
                                                  float* __restrict__ dinv, float* __restrict__ dinv2, int N) {
    int n = blockIdx.x * 256 + threadIdx.x;
    if (n < N) {
        int b = rowp[n], e = rowp[n + 1];
        float s = 0.f;
        for (int p = b; p < e; p++) s += __int_as_float(cpack[p].y);
        float di = rsqrtf(s + 1.0f);
        dinv[n] = di;
        dinv2[n] = di * di;
    }
}

// ---------------- edge-weight precompute (node-parallel, wave per dst node) ----------------

template <int H>
__global__ __launch_bounds__(NPB * 64) void k_edge_gat_n(const int* __restrict__ rowp, const int2* __restrict__ cpack,
                                                         const float* __restrict__ as_, const float* __restrict__ ad_,
                                                         float* __restrict__ ew, int N) {
    int n = blockIdx.x * NPB + (threadIdx.x >> 6);
    if (n >= N) return;
    int lane = threadIdx.x & 63;
    float adn[H], msub[H];
#pragma unroll
    for (int h = 0; h < H; h++) {
        adn[h] = ad_[(size_t)n * H + h];
        msub[h] = lrelu02(as_[(size_t)n * H + h] + adn[h]);
    }
    int beg = rowp[n], end = rowp[n + 1];
    for (int base = beg; base < end; base += WAVE) {
        int cnt = end - base;
        if (cnt > WAVE) cnt = WAVE;
        if (lane < cnt) {
            int s = cpack[base + lane].x;
            if (H == 2) {
                float2 o;
                o.x = __expf(lrelu02(as_[(size_t)s * 2 + 0] + adn[0]) - msub[0]);
                o.y = __expf(lrelu02(as_[(size_t)s * 2 + 1] + adn[1]) - msub[1]);
                *(float2*)(ew + (size_t)(base + lane) * 2) = o;
            } else {
                ew[base + lane] = __expf(lrelu02(as_[s] + adn[0]) - msub[0]);
            }
        }
    }
}

__global__ __launch_bounds__(NPB * 64) void k_edge_gcn_n(const int* __restrict__ rowp, const int2* __restrict__ cpack,
                                                         const float* __restrict__ dinv,
                                                         float* __restrict__ ew, int N) {
    int n = blockIdx.x * NPB + (threadIdx.x >> 6);
    if (n >= N) return;
    int lane = threadIdx.x & 63;
    float di = dinv[n];
    int beg = rowp[n], end = rowp[n + 1];
    for (int base = beg; base < end; base += WAVE) {
        int cnt = end - base;
        if (cnt > WAVE) cnt = WAVE;
        if (lane < cnt) {
            int2 pk = cpack[base + lane];
            ew[base + lane] = dinv[pk.x] * __int_as_float(pk.y) * di;
        }
    }
}

// ---------------- merged conversions (weight dims are compile-time constants) ----------------

__device__ __forceinline__ void cvtw1(const float* __restrict__ W, unsigned short* __restrict__ WT,
                                      int K, int M, int Kp, int i) {
    int m = i / Kp;
    int k = i - m * Kp;
    WT[i] = (k < K) ? f2bf(W[(long long)k * M + m]) : (unsigned short)0;
}

__global__ __launch_bounds__(256) void k_cvt_w_all(const float* __restrict__ W1, const float* __restrict__ W2,
                                                   const float* __restrict__ W3, const float* __restrict__ Wp1,
                                                   const float* __restrict__ Wp2, const float* __restrict__ Wp3,
                                                   unsigned short* __restrict__ wt1, unsigned short* __restrict__ wt2,
                                                   unsigned short* __restrict__ wt3, unsigned short* __restrict__ wtp1,
                                                   unsigned short* __restrict__ wtp2, unsigned short* __restrict__ wtp3) {
    int idx = blockIdx.x * 256 + threadIdx.x;
    if (idx < 12480)        cvtw1(W1, wt1, 78, 156, 80, idx);
    else if (idx < 62400)   cvtw1(W2, wt2, 156, 312, 160, idx - 12480);
    else if (idx < 162240)  cvtw1(W3, wt3, 312, 312, 320, idx - 62400);
    else if (idx < 163560)  cvtw1(Wp1, wtp1, 33, 33, 40, idx - 162240);
    else if (idx < 168840)  cvtw1(Wp2, wtp2, 33, 132, 40, idx - 163560);
    else if (idx < 186792)  cvtw1(Wp3, wtp3, 132, 132, 136, idx - 168840);
}

__device__ __forceinline__ void prep1(const float* __restrict__ W, const float* __restrict__ a_src,
                                      const float* __restrict__ a_dst, unsigned short* __restrict__ WT,
                                      int K, int M, int C, int Kp, int H, int b, int lane) {
    int k = b % Kp;
    int th = b / Kp;
    int t = th / H;
    int h = th - t * H;
    size_t orow = (size_t)(M + t * H + h) * Kp;
    if (k >= K) {
        if (lane == 0) WT[orow + k] = 0;
        return;
    }
    const float* a = t ? a_dst : a_src;
    int hoff = h * C;
    const float* wrow = W + (size_t)k * M + hoff;
    float acc = 0.f;
    for (int c = lane; c < C; c += 64) acc += wrow[c] * a[hoff + c];
    for (int off = 32; off > 0; off >>= 1) acc += __shfl_down(acc, off);
    if (lane == 0) WT[orow + k] = f2bf(acc);
}

__global__ __launch_bounds__(64) void k_prep_va_all(const float* __restrict__ W1, const float* __restrict__ as1,
                                                    const float* __restrict__ ad1, unsigned short* __restrict__ wt1,
                                                    const float* __restrict__ W2, const float* __restrict__ as2,
                                                    const float* __restrict__ ad2, unsigned short* __restrict__ wt2,
                                                    const float* __restrict__ W3, const float* __restrict__ as3,
                                                    const float* __restrict__ ad3, unsigned short* __restrict__ wt3,
                                                    const float* __restrict__ Wp2, const float* __restrict__ aps2,
                                                    const float* __restrict__ apd2, unsigned short* __restrict__ wtp2,
                                                    const float* __restrict__ Wp3, const float* __restrict__ aps3,
                                                    const float* __restrict__ apd3, unsigned short* __restrict__ wtp3) {
    int b = blockIdx.x;
    int lane = threadIdx.x;
    if (b < 320)        prep1(W1, as1, ad1, wt1, 78, 156, 78, 80, 2, b, lane);
    else if (b < 960)   prep1(W2, as2, ad2, wt2, 156, 312, 156, 160, 2, b - 320, lane);
    else if (b < 1600)  prep1(W3, as3, ad3, wt3, 312, 312, 312, 320, 1, b - 960, lane);
    else if (b < 1760)  prep1(Wp2, aps2, apd2, wtp2, 33, 132, 66, 40, 2, b - 1600, lane);
    else                prep1(Wp3, aps3, apd3, wtp3, 132, 132, 132, 136, 1, b - 1760, lane);
}

__global__ __launch_bounds__(256) void k_cvt_x_all(const float* __restrict__ mol_x, unsigned short* __restrict__ xb,
                                                   const float* __restrict__ pro_x, unsigned short* __restrict__ xp,
                                                   long long totM, long long totP) {
    long long idx = (long long)blockIdx.x * 256 + threadIdx.x;
    if (idx < totM) {
        int n = (int)(idx / 80);
        int k = (int)(idx - (long long)n * 80);
        xb[idx] = (k < 78) ? f2bf(mol_x[(long long)n * 78 + k]) : (unsigned short)0;
    } else if (idx < totM + totP) {
        long long i2 = idx - totM;
        int n = (int)(i2 / 40);
        int k = (int)(i2 - (long long)n * 40);
        xp[i2] = (k < 33) ? f2bf(pro_x[(long long)n * 33 + k]) : (unsigned short)0;
    }
}

// ---------------- bf16 MFMA GEMM + alpha epilogue ----------------

#define TBM 128
#define TBN 128
#define TBK 32
#define LDK 40

__global__ __launch_bounds__(256) void k_mfma_gemm(const unsigned short* __restrict__ A,
                                                   const unsigned short* __restrict__ BT,
                                                   unsigned short* __restrict__ Cbf,
                                                   float* __restrict__ asb, float* __restrict__ adb,
                                                   int N, int Kp, int M, int Mext, int Mp, int H) {
    __shared__ __align__(16) unsigned short As[TBM * LDK];
    __shared__ __align__(16) unsigned short Bs[TBN * LDK];
    int tid = threadIdx.x;
    int wave = tid >> 6;
    int lane = tid & 63;
    int rowBase = blockIdx.y * TBM;
    int colBase = blockIdx.x * TBN;
    int wm = (wave & 1) * 64;
    int wn = (wave >> 1) * 64;
    int l15 = lane & 15;
    int quad = lane >> 4;

    f32x4 acc[4][4];
    f32x4 z4 = {0.f, 0.f, 0.f, 0.f};
#pragma unroll
    for (int i = 0; i < 4; i++)
#pragma unroll
        for (int j = 0; j < 4; j++) acc[i][j] = z4;

    int srow = tid >> 2;
    int skg = tid & 3;
    const uint4 zero16 = {0u, 0u, 0u, 0u};

    for (int k0 = 0; k0 < Kp; k0 += TBK) {
#pragma unroll
        for (int half = 0; half < 2; half++) {
            int row = srow + half * 64;
            int gk = k0 + skg * 8;
            bool kok = (gk < Kp);
            {
                int gr = rowBase + row;
                uint4 v = zero16;
                if (kok && gr < N) v = *(const uint4*)(A + (size_t)gr * Kp + gk);
                *(uint4*)(As + row * LDK + skg * 8) = v;
            }
            {
                int gc = colBase + row;
                uint4 v = zero16;
                if (kok && gc < Mext) v = *(const uint4*)(BT + (size_t)gc * Kp + gk);
                *(uint4*)(Bs + row * LDK + skg * 8) = v;
            }
        }
        __syncthreads();

        s16x8 af[4], bfr[4];
#pragma unroll
        for (int mt = 0; mt < 4; mt++)
            af[mt] = *(const s16x8*)(As + (wm + mt * 16 + l15) * LDK + quad * 8);
#pragma unroll
        for (int nt = 0; nt < 4; nt++)
            bfr[nt] = *(const s16x8*)(Bs + (wn + nt * 16 + l15) * LDK + quad * 8);
#pragma unroll
        for (int mt = 0; mt < 4; mt++)
#pragma unroll
            for (int nt = 0; nt < 4; nt++)
                acc[mt][nt] = __builtin_amdgcn_mfma_f32_16x16x32_bf16(af[mt], bfr[nt], acc[mt][nt], 0, 0, 0);
        __syncthreads();
    }

#pragma unroll
    for (int mt = 0; mt < 4; mt++) {
#pragma unroll
        for (int r = 0; r < 4; r++) {
            int row = rowBase + wm + mt * 16 + quad * 4 + r;
            if (row < N) {
#pragma unroll
                for (int nt = 0; nt < 4; nt++) {
                    int col = colBase + wn + nt * 16 + l15;
                    float v = acc[mt][nt][r];
                    if (col < M) {
                        Cbf[(size_t)row * Mp + col] = f2bf(v);
                    } else if (asb != nullptr && col < M + 2 * H) {
                        int t = col - M;
                        if (t < H) asb[(size_t)row * H + t] = v;
                        else adb[(size_t)row * H + (t - H)] = v;
                    }
                }
            }
        }
    }
}

// ---------------- packed aggregation: G edges per wave, dwordx4 gathers ----------------
// Lane layout: lane = g*SLOTS + slot. Full feature row = SWEEPS*SLOTS uint4s (8 bf16 each);
// ONE wave per node sweeps the row SWEEPS times per gathered edge (prologue/edge machinery
// paid once per node). One gather instruction covers G edges' worth of one sweep.

template <int SLOTS, int G, int H, bool SM, int SWEEPS>
__global__ __launch_bounds__(NPB * 64) void k_agg4(const unsigned short* __restrict__ hfeat,
                                                   const float* __restrict__ ew,
                                                   const float* __restrict__ selfw,  // used when !SM
                                                   const int* __restrict__ rowp, const int2* __restrict__ cpack,
                                                   const float* __restrict__ bias,
                                                   float* __restrict__ out_f,
                                                   unsigned short* __restrict__ out_bf,
                                                   int HC, int ldo, int relu, int N) {
    int n = blockIdx.x * NPB + (threadIdx.x >> 6);
    if (n >= N) return;
    int lane = threadIdx.x & 63;
    constexpr int ROWB = SWEEPS * SLOTS * 16;  // full row bytes
    int g = lane / SLOTS;
    int slot = lane - g * SLOTS;
    bool act = (g < G);
    int C = HC / H;
    int beg = rowp[n], end = rowp[n + 1];

    int ch0[SWEEPS];
    bool h1q[SWEEPS][4];
#pragma unroll
    for (int sw = 0; sw < SWEEPS; sw++) {
        ch0[sw] = (sw * SLOTS + slot) * 8;
#pragma unroll
        for (int q = 0; q < 4; q++) h1q[sw][q] = (H == 2) && ((ch0[sw] + 2 * q) >= C);
    }

    float sfw = SM ? 1.f : selfw[n];
    float accx[SWEEPS][4], accy[SWEEPS][4];
#pragma unroll
    for (int sw = 0; sw < SWEEPS; sw++)
#pragma unroll
        for (int q = 0; q < 4; q++) { accx[sw][q] = 0.f; accy[sw][q] = 0.f; }
    if (act && g == 0) {
#pragma unroll
        for (int sw = 0; sw < SWEEPS; sw++) {
            uint4 v = *(const uint4*)((const char*)hfeat + (size_t)n * ROWB + (sw * SLOTS + slot) * 16);
            unsigned int vv[4] = {v.x, v.y, v.z, v.w};
#pragma unroll
            for (int q = 0; q < 4; q++) { accx[sw][q] = sfw * bf2f_lo(vv[q]); accy[sw][q] = sfw * bf2f_hi(vv[q]); }
        }
    }

    float wsum[H];
#pragma unroll
    for (int h = 0; h < H; h++) wsum[h] = 0.f;

    for (int base = beg; base < end; base += WAVE) {
        int cnt = end - base;
        if (cnt > WAVE) cnt = WAVE;
        int s_l = 0;
        float w_l[H];
#pragma unroll
        for (int h = 0; h < H; h++) w_l[h] = 0.f;
        if (lane < cnt) {
            s_l = cpack[base + lane].x;
            if (H == 2) {
                float2 t = *(const float2*)(ew + (size_t)(base + lane) * 2);
                w_l[0] = t.x;
                w_l[1] = t.y;
                if (SM) { wsum[0] += t.x; wsum[1] += t.y; }
            } else {
                w_l[0] = ew[base + lane];
                if (SM) wsum[0] += w_l[0];
            }
        }
        for (int j0 = 0; j0 < cnt; j0 += 2 * G) {
            // group A
            int sA;
            float wA[H];
            uint4 vA[SWEEPS];
            {
                int jj = j0 + g;
                bool pad = (jj >= cnt);
                if (jj > cnt - 1) jj = cnt - 1;
                int ba = jj << 2;
                sA = __builtin_amdgcn_ds_bpermute(ba, s_l);
#pragma unroll
                for (int h = 0; h < H; h++) {
                    float t = __uint_as_float(
                        (unsigned)__builtin_amdgcn_ds_bpermute(ba, (int)__float_as_uint(w_l[h])));
                    wA[h] = pad ? 0.f : t;
                }
                if (act) {
#pragma unroll
                    for (int sw = 0; sw < SWEEPS; sw++) {
                        unsigned voff = (unsigned)sA * ROWB + (sw * SLOTS + slot) * 16;
                        vA[sw] = *(const uint4*)((const char*)hfeat + voff);
                    }
                }
            }
            // group B (uniform predicate)
            bool haveB = (j0 + G < cnt);
            int sB;
            float wB[H];
            uint4 vB[SWEEPS];
            if (haveB) {
                int jj = j0 + G + g;
                bool pad = (jj >= cnt);
                if (jj > cnt - 1) jj = cnt - 1;
                int ba = jj << 2;
                sB = __builtin_amdgcn_ds_bpermute(ba, s_l);
#pragma unroll
                for (int h = 0; h < H; h++) {
                    float t = __uint_as_float(
                        (unsigned)__builtin_amdgcn_ds_bpermute(ba, (int)__float_as_uint(w_l[h])));
                    wB[h] = pad ? 0.f : t;
                }
                if (act) {
#pragma unroll
                    for (int sw = 0; sw < SWEEPS; sw++) {
                        unsigned voff = (unsigned)sB * ROWB + (sw * SLOTS + slot) * 16;
                        vB[sw] = *(const uint4*)((const char*)hfeat + voff);
                    }
                }
            }
            if (act) {
#pragma unroll
                for (int sw = 0; sw < SWEEPS; sw++) {
                    unsigned int va[4] = {vA[sw].x, vA[sw].y, vA[sw].z, vA[sw].w};
#pragma unroll
                    for (int q = 0; q < 4; q++) {
                        float wq = (H == 2) ? (h1q[sw][q] ? wA[1] : wA[0]) : wA[0];
                        accx[sw][q] += wq * bf2f_lo(va[q]);
                        accy[sw][q] += wq * bf2f_hi(va[q]);
                    }
                }
                if (haveB) {
#pragma unroll
                    for (int sw = 0; sw < SWEEPS; sw++) {
                        unsigned int ub[4] = {vB[sw].x, vB[sw].y, vB[sw].z, vB[sw].w};
#pragma unroll
                        for (int q = 0; q < 4; q++) {
                            float wq = (H == 2) ? (h1q[sw][q] ? wB[1] : wB[0]) : wB[0];
                            accx[sw][q] += wq * bf2f_lo(ub[q]);
                            accy[sw][q] += wq * bf2f_hi(ub[q]);
                        }
                    }
                }
            }
        }
    }

    // cross-group channel reduction into lanes [0, SLOTS)
    if (G == 3) {
#pragma unroll
        for (int sw = 0; sw < SWEEPS; sw++)
#pragma unroll
            for (int q = 0; q < 4; q++) {
                int b1a = (lane + SLOTS) << 2, b2a = (lane + 2 * SLOTS) << 2;
                float t1 = __uint_as_float((unsigned)__builtin_amdgcn_ds_bpermute(b1a, (int)__float_as_uint(accx[sw][q])));
                float t2 = __uint_as_float((unsigned)__builtin_amdgcn_ds_bpermute(b2a, (int)__float_as_uint(accx[sw][q])));
                accx[sw][q] += t1 + t2;
                float t3 = __uint_as_float((unsigned)__builtin_amdgcn_ds_bpermute(b1a, (int)__float_as_uint(accy[sw][q])));
                float t4 = __uint_as_float((unsigned)__builtin_amdgcn_ds_bpermute(b2a, (int)__float_as_uint(accy[sw][q])));
                accy[sw][q] += t3 + t4;
            }
    } else if (G == 8) {
#pragma unroll
        for (int st = 4; st >= 1; st >>= 1) {
            int ba = (lane + st * SLOTS) << 2;
#pragma unroll
            for (int sw = 0; sw < SWEEPS; sw++)
#pragma unroll
                for (int q = 0; q < 4; q++) {
                    accx[sw][q] += __uint_as_float((unsigned)__builtin_amdgcn_ds_bpermute(ba, (int)__float_as_uint(accx[sw][q])));
                    accy[sw][q] += __uint_as_float((unsigned)__builtin_amdgcn_ds_bpermute(ba, (int)__float_as_uint(accy[sw][q])));
                }
        }
    }

    float rs[H];
    if (SM) {
#pragma unroll
        for (int h = 0; h < H; h++) {
            float t = wsum[h];
            for (int off = 32; off > 0; off >>= 1) t += __shfl_xor(t, off);
            rs[h] = 1.f / (1.f + t + 1e-16f);  // +1 = self term
        }
    } else {
#pragma unroll
        for (int h = 0; h < H; h++) rs[h] = 1.f;
    }

    if (lane < SLOTS) {
#pragma unroll
        for (int sw = 0; sw < SWEEPS; sw++) {
            float o[8];
#pragma unroll
            for (int q = 0; q < 4; q++) {
                float r = (H == 2) ? (h1q[sw][q] ? rs[1] : rs[0]) : rs[0];
                int c0 = ch0[sw] + 2 * q;
                float b0 = (c0 < HC) ? bias[c0] : 0.f;
                float b1v = (c0 + 1 < HC) ? bias[c0 + 1] : 0.f;
                float o0 = accx[sw][q] * r + b0;
                float o1 = accy[sw][q] * r + b1v;
                if (relu) { o0 = fmaxf(o0, 0.f); o1 = fmaxf(o1, 0.f); }
                if (c0 >= HC) o0 = 0.f;
                if (c0 + 1 >= HC) o1 = 0.f;
                o[2 * q] = o0;
                o[2 * q + 1] = o1;
            }
            if (out_bf) {
                uint4 pk;
                unsigned* pp = (unsigned*)&pk;
#pragma unroll
                for (int q = 0; q < 4; q++)
                    pp[q] = (unsigned)f2bf(o[2 * q]) | ((unsigned)f2bf(o[2 * q + 1]) << 16);
                *(uint4*)((char*)out_bf + (size_t)n * ((size_t)ldo * 2) + (sw * SLOTS + slot) * 16) = pk;
            } else {
#pragma unroll
                for (int half = 0; half < 2; half++) {
                    int c0 = ch0[sw] + half * 4;
                    if (c0 < HC) {
                        float4 f4 = make_float4(o[half * 4], o[half * 4 + 1], o[half * 4 + 2], o[half * 4 + 3]);
                        *(float4*)(out_f + (size_t)n * HC + c0) = f4;
                    }
                }
            }
        }
    }
}

// ---------------- launch ----------------

extern "C" void kernel_launch(void* const* d_in, const int* in_sizes, int n_in,
                              void* d_out, int out_size, void* d_ws, size_t ws_size,
                              hipStream_t stream) {
    const int N_MOL = in_sizes[0] / 78;
    const int E_MOL = in_sizes[1] / 2;
    const int N_PRO = in_sizes[2] / 33;
    const int E_PRO = in_sizes[3] / 2;
    const int NT = N_MOL + N_PRO;
    const int ET = E_MOL + E_PRO;

    const float* mol_x = (const float*)d_in[0];
    const int* mol_ei = (const int*)d_in[1];
    const float* pro_x = (const float*)d_in[2];
    const int* pro_ei = (const int*)d_in[3];
    const float* pro_ew = (const float*)d_in[4];
    const float *W1 = (const float*)d_in[5], *as1 = (const float*)d_in[6], *ad1 = (const float*)d_in[7],
                *b1 = (const float*)d_in[8];
    const float *W2 = (const float*)d_in[9], *as2 = (const float*)d_in[10], *ad2 = (const float*)d_in[11],
                *b2 = (const float*)d_in[12];
    const float *W3 = (const float*)d_in[13], *as3 = (const float*)d_in[14], *ad3 = (const float*)d_in[15],
                *b3 = (const float*)d_in[16];
    const float *Wp1 = (const float*)d_in[17], *bp1 = (const float*)d_in[18];
    const float *Wp2 = (const float*)d_in[19], *aps2 = (const float*)d_in[20], *apd2 = (const float*)d_in[21],
                *bp2 = (const float*)d_in[22];
    const float *Wp3 = (const float*)d_in[23], *aps3 = (const float*)d_in[24], *apd3 = (const float*)d_in[25],
                *bp3 = (const float*)d_in[26];

    float* out_mol = (float*)d_out;
    float* out_pro = (float*)d_out + (size_t)N_MOL * 312;

    char* p = (char*)d_ws;
    auto alloc = [&](size_t bytes) -> void* {
        void* r = (void*)p;
        p += (bytes + 255) & ~(size_t)255;
        return r;
    };
    int* cnt_all  = (int*)alloc((size_t)NT * 4);
    int* incl     = (int*)alloc((size_t)NT * 4);
    int* cur_all  = (int*)alloc((size_t)NT * 4);
    int* bsums    = (int*)alloc(1024 * 4);
    int* mol_rowp = (int*)alloc((size_t)(N_MOL + 1) * 4);
    int* pro_rowp = (int*)alloc((size_t)(N_PRO + 1) * 4);
    int2* cpack   = (int2*)alloc((size_t)ET * 8);
    float* dinv   = (float*)alloc((size_t)N_PRO * 4);
    float* dinv2  = (float*)alloc((size_t)N_PRO * 4);
    float* asb = (float*)alloc((size_t)N_PRO * 2 * 4);
    float* adb = (float*)alloc((size_t)N_PRO * 2 * 4);
    float* ewb = (float*)alloc((size_t)E_PRO * 2 * 4);  // edge weights (reused sequentially)
    unsigned short* hb = (unsigned short*)alloc((size_t)N_MOL * 320 * 2);
    unsigned short* xb = (unsigned short*)alloc((size_t)N_MOL * 320 * 2);  // activations (mol, then pro)
    unsigned short* xp = (unsigned short*)alloc((size_t)N_PRO * 40 * 2);   // pro input bf16
    unsigned short* wt1 = (unsigned short*)alloc((size_t)160 * 80 * 2);
    unsigned short* wt2 = (unsigned short*)alloc((size_t)320 * 160 * 2);
    unsigned short* wt3 = (unsigned short*)alloc((size_t)320 * 320 * 2);
    unsigned short* wtp1 = (unsigned short*)alloc((size_t)40 * 40 * 2);
    unsigned short* wtp2 = (unsigned short*)alloc((size_t)136 * 40 * 2);
    unsigned short* wtp3 = (unsigned short*)alloc((size_t)136 * 136 * 2);
    (void)ws_size;

    int2* mol_cp = cpack;            // mol edges at [0, E_MOL)
    int2* pro_cp = cpack + E_MOL;    // pro edges at [E_MOL, ET), local pointers

    const int* mol_src = mol_ei;
    const int* mol_dst = mol_ei + E_MOL;
    const int* pro_src = pro_ei;
    const int* pro_dst = pro_ei + E_PRO;

    // ---- fused CSR build ----
    hipMemsetAsync(cnt_all, 0, (size_t)NT * 4, stream);
    k_count_all<<<(ET + 1023) / 1024, 256, 0, stream>>>(mol_dst, pro_dst, cnt_all, N_MOL, E_MOL, ET);
    int nbT = (NT + 255) / 256;
    k_scan1<<<nbT, 256, 0, stream>>>(cnt_all, incl, bsums, NT);
    k_scan2<<<1, 1024, 0, stream>>>(bsums, nbT);
    k_scan3_all<<<nbT, 256, 0, stream>>>(incl, cnt_all, bsums, mol_rowp, pro_rowp, cur_all,
                                         N_MOL, N_PRO, E_MOL, E_PRO);
    k_scatter_all<<<(ET + 255) / 256, 256, 0, stream>>>(mol_src, mol_dst, pro_src, pro_dst, pro_ew,
                                                        cur_all, cpack, N_MOL, E_MOL, ET);
    k_deg_dinv<<<(N_PRO + 255) / 256, 256, 0, stream>>>(pro_rowp, pro_cp, dinv, dinv2, N_PRO);

    // ---- merged weight converts + alpha rows + input converts ----
    k_cvt_w_all<<<730, 256, 0, stream>>>(W1, W2, W3, Wp1, Wp2, Wp3, wt1, wt2, wt3, wtp1, wtp2, wtp3);
    k_prep_va_all<<<2032, 64, 0, stream>>>(W1, as1, ad1, wt1, W2, as2, ad2, wt2, W3, as3, ad3, wt3,
                                           Wp2, aps2, apd2, wtp2, Wp3, aps3, apd3, wtp3);
    {
        long long totM = (long long)N_MOL * 80;
        long long totP = (long long)N_PRO * 40;
        k_cvt_x_all<<<(int)((totM + totP + 255) / 256), 256, 0, stream>>>(mol_x, xb, pro_x, xp, totM, totP);
    }

    auto gemm = [&](const unsigned short* A, const unsigned short* BT, unsigned short* C,
                    float* as_o, float* ad_o, int N, int Kp, int M, int Mp, int H) {
        int Mext = (as_o != nullptr) ? (M + 2 * H) : M;
        dim3 grid((Mext + TBN - 1) / TBN, (N + TBM - 1) / TBM);
        k_mfma_gemm<<<grid, 256, 0, stream>>>(A, BT, C, as_o, ad_o, N, Kp, M, Mext, Mp, H);
    };

    auto waves = [](int items) { return dim3((items + NPB - 1) / NPB); };

    // ---- mol branch ----
    // conv1: GAT 78 -> 78, H=2 (HC=156, row 160 = 20 slots x 1 sweep), relu
    gemm(xb, wt1, hb, asb, adb, N_MOL, 80, 156, 160, 2);
    k_edge_gat_n<2><<<waves(N_MOL), NPB * 64, 0, stream>>>(mol_rowp, mol_cp, asb, adb, ewb, N_MOL);
    k_agg4<20, 3, 2, true, 1><<<waves(N_MOL), NPB * 64, 0, stream>>>(hb, ewb, nullptr, mol_rowp, mol_cp, b1,
                                                                     nullptr, xb, 156, 160, 1, N_MOL);
    // conv2: GAT 156 -> 156, H=2 (HC=312, row 320 = 20 slots x 2 sweeps), relu
    gemm(xb, wt2, hb, asb, adb, N_MOL, 160, 312, 320, 2);
    k_edge_gat_n<2><<<waves(N_MOL), NPB * 64, 0, stream>>>(mol_rowp, mol_cp, asb, adb, ewb, N_MOL);
    k_agg4<20, 3, 2, true, 2><<<waves(N_MOL), NPB * 64, 0, stream>>>(hb, ewb, nullptr, mol_rowp, mol_cp, b2,
                                                                     nullptr, xb, 312, 320, 1, N_MOL);
    // conv3: GAT 312 -> 312, H=1, no relu -> fp32 out
    gemm(xb, wt3, hb, asb, adb, N_MOL, 320, 312, 320, 1);
    k_edge_gat_n<1><<<waves(N_MOL), NPB * 64, 0, stream>>>(mol_rowp, mol_cp, asb, adb, ewb, N_MOL);
    k_agg4<20, 3, 1, true, 2><<<waves(N_MOL), NPB * 64, 0, stream>>>(hb, ewb, nullptr, mol_rowp, mol_cp, b3,
                                                                     out_mol, nullptr, 312, 320, 0, N_MOL);

    // ---- pro branch ----
    // gcn: 33 -> 33 (row 40 = 5 slots, G=8), relu
    gemm(xp, wtp1, hb, nullptr, nullptr, N_PRO, 40, 33, 40, 0);
    k_edge_gcn_n<<<waves(N_PRO), NPB * 64, 0, stream>>>(pro_rowp, pro_cp, dinv, ewb, N_PRO);
    k_agg4<5, 8, 1, false, 1><<<waves(N_PRO), NPB * 64, 0, stream>>>(hb, ewb, dinv2, pro_rowp, pro_cp, bp1,
                                                                     nullptr, xb, 33, 40, 1, N_PRO);
    // conv2: GAT 33 -> 66, H=2 (HC=132, row 136 = 17 slots), relu
    gemm(xb, wtp2, hb, asb, adb, N_PRO, 40, 132, 136, 2);
    k_edge_gat_n<2><<<waves(N_PRO), NPB * 64, 0, stream>>>(pro_rowp, pro_cp, asb, adb, ewb, N_PRO);
    k_agg4<17, 3, 2, true, 1><<<waves(N_PRO), NPB * 64, 0, stream>>>(hb, ewb, nullptr, pro_rowp, pro_cp, bp2,
                                                                     nullptr, xb, 132, 136, 1, N_PRO);
    // conv3: GAT 132 -> 132, H=1, relu -> fp32 out
    gemm(xb, wtp3, hb, asb, adb, N_PRO, 136, 132, 136, 1);
    k_edge_gat_n<1><<<waves(N_PRO), NPB * 64, 0, stream>>>(pro_rowp, pro_cp, asb, adb, ewb, N_PRO);
    k_agg4<17, 3, 1, true, 1><<<waves(N_PRO), NPB * 64, 0, stream>>>(hb, ewb, nullptr, pro_rowp, pro_cp, bp3,
                                                                     out_pro, nullptr, 132, 136, 1, N_PRO);
}

// Round 5
// 764.674 us; speedup vs baseline: 1.1709x; 1.1379x over previous
//
#include <hip/hip_runtime.h>
#include <cstdint>
#include <cstddef>

#define WAVE 64
#define NPB 4   // waves per aggregation block

#define TBM 128
#define TBN 128
#define TBK 32
#define LDK 40

typedef short s16x8 __attribute__((ext_vector_type(8)));
typedef float f32x4 __attribute__((ext_vector_type(4)));

__device__ __forceinline__ unsigned short f2bf(float f) {
    unsigned int u = __float_as_uint(f);
    unsigned int r = (u + 0x7fffu + ((u >> 16) & 1u)) >> 16;
    return (unsigned short)r;
}
__device__ __forceinline__ float bf2f_lo(unsigned int v) { return __uint_as_float(v << 16); }
__device__ __forceinline__ float bf2f_hi(unsigned int v) { return __uint_as_float(v & 0xffff0000u); }
__device__ __forceinline__ float lrelu02(float e) { return (e > 0.f) ? e : 0.2f * e; }

// ==================== GEMM body (device fn; static LDS) ====================

__device__ __forceinline__ void gemm_body(const unsigned short* __restrict__ A,
                                          const unsigned short* __restrict__ BT,
                                          unsigned short* __restrict__ Cbf,
                                          float* __restrict__ asb, float* __restrict__ adb,
                                          int N, int Kp, int M, int Mext, int Mp, int H,
                                          int bx, int by) {
    __shared__ __align__(16) unsigned short As[TBM * LDK];
    __shared__ __align__(16) unsigned short Bs[TBN * LDK];
    int tid = threadIdx.x;
    int wave = tid >> 6;
    int lane = tid & 63;
    int rowBase = by * TBM;
    int colBase = bx * TBN;
    int wm = (wave & 1) * 64;
    int wn = (wave >> 1) * 64;
    int l15 = lane & 15;
    int quad = lane >> 4;

    f32x4 acc[4][4];
    f32x4 z4 = {0.f, 0.f, 0.f, 0.f};
#pragma unroll
    for (int i = 0; i < 4; i++)
#pragma unroll
        for (int j = 0; j < 4; j++) acc[i][j] = z4;

    int srow = tid >> 2;
    int skg = tid & 3;
    const uint4 zero16 = {0u, 0u, 0u, 0u};

    for (int k0 = 0; k0 < Kp; k0 += TBK) {
#pragma unroll
        for (int half = 0; half < 2; half++) {
            int row = srow + half * 64;
            int gk = k0 + skg * 8;
            bool kok = (gk < Kp);
            {
                int gr = rowBase + row;
                uint4 v = zero16;
                if (kok && gr < N) v = *(const uint4*)(A + (size_t)gr * Kp + gk);
                *(uint4*)(As + row * LDK + skg * 8) = v;
            }
            {
                int gc = colBase + row;
                uint4 v = zero16;
                if (kok && gc < Mext) v = *(const uint4*)(BT + (size_t)gc * Kp + gk);
                *(uint4*)(Bs + row * LDK + skg * 8) = v;
            }
        }
        __syncthreads();

        s16x8 af[4], bfr[4];
#pragma unroll
        for (int mt = 0; mt < 4; mt++)
            af[mt] = *(const s16x8*)(As + (wm + mt * 16 + l15) * LDK + quad * 8);
#pragma unroll
        for (int nt = 0; nt < 4; nt++)
            bfr[nt] = *(const s16x8*)(Bs + (wn + nt * 16 + l15) * LDK + quad * 8);
#pragma unroll
        for (int mt = 0; mt < 4; mt++)
#pragma unroll
            for (int nt = 0; nt < 4; nt++)
                acc[mt][nt] = __builtin_amdgcn_mfma_f32_16x16x32_bf16(af[mt], bfr[nt], acc[mt][nt], 0, 0, 0);
        __syncthreads();
    }

#pragma unroll
    for (int mt = 0; mt < 4; mt++) {
#pragma unroll
        for (int r = 0; r < 4; r++) {
            int row = rowBase + wm + mt * 16 + quad * 4 + r;
            if (row < N) {
#pragma unroll
                for (int nt = 0; nt < 4; nt++) {
                    int col = colBase + wn + nt * 16 + l15;
                    float v = acc[mt][nt][r];
                    if (col < M) {
                        Cbf[(size_t)row * Mp + col] = f2bf(v);
                    } else if (asb != nullptr && col < M + 2 * H) {
                        int t = col - M;
                        if (t < H) asb[(size_t)row * H + t] = v;
                        else adb[(size_t)row * H + (t - H)] = v;
                    }
                }
            }
        }
    }
}

// ==================== packed aggregation body (inline edge weights) ====================
// Lane layout: lane = g*SLOTS + slot. Full row = SWEEPS*SLOTS uint4s (8 bf16 each).
// GCN=false: GAT — weights exp(lrelu(as[s]+ad[n]) - msub) computed inline (as_/ad_ gathers).
// GCN=true:  weights dinv[s]*w*dinv[n], self = dinv[n]^2, no softmax.

template <int SLOTS, int G, int H, bool SM, int SWEEPS, bool GCN>
__device__ __forceinline__ void agg_body(const unsigned short* __restrict__ hfeat,
                                         const float* __restrict__ as_, const float* __restrict__ ad_,
                                         const float* __restrict__ dinv,
                                         const int* __restrict__ rowp, const int2* __restrict__ cpack,
                                         const float* __restrict__ bias,
                                         float* __restrict__ out_f, unsigned short* __restrict__ out_bf,
                                         int HC, int ldo, int relu, int n, int lane) {
    constexpr int ROWB = SWEEPS * SLOTS * 16;
    int g = lane / SLOTS;
    int slot = lane - g * SLOTS;
    bool act = (g < G);
    int C = HC / H;
    int beg = rowp[n], end = rowp[n + 1];

    float adn[H], msub[H];
    float di = 0.f;
    if (GCN) {
        di = dinv[n];
    } else {
#pragma unroll
        for (int h = 0; h < H; h++) {
            adn[h] = ad_[(size_t)n * H + h];
            msub[h] = lrelu02(as_[(size_t)n * H + h] + adn[h]);
        }
    }

    int ch0[SWEEPS];
    bool h1q[SWEEPS][4];
#pragma unroll
    for (int sw = 0; sw < SWEEPS; sw++) {
        ch0[sw] = (sw * SLOTS + slot) * 8;
#pragma unroll
        for (int q = 0; q < 4; q++) h1q[sw][q] = (H == 2) && ((ch0[sw] + 2 * q) >= C);
    }

    float sfw = GCN ? di * di : 1.f;
    float accx[SWEEPS][4], accy[SWEEPS][4];
#pragma unroll
    for (int sw = 0; sw < SWEEPS; sw++)
#pragma unroll
        for (int q = 0; q < 4; q++) { accx[sw][q] = 0.f; accy[sw][q] = 0.f; }
    if (act && g == 0) {
#pragma unroll
        for (int sw = 0; sw < SWEEPS; sw++) {
            uint4 v = *(const uint4*)((const char*)hfeat + (size_t)n * ROWB + (sw * SLOTS + slot) * 16);
            unsigned int vv[4] = {v.x, v.y, v.z, v.w};
#pragma unroll
            for (int q = 0; q < 4; q++) { accx[sw][q] = sfw * bf2f_lo(vv[q]); accy[sw][q] = sfw * bf2f_hi(vv[q]); }
        }
    }

    float wsum[H];
#pragma unroll
    for (int h = 0; h < H; h++) wsum[h] = 0.f;

    for (int base = beg; base < end; base += WAVE) {
        int cnt = end - base;
        if (cnt > WAVE) cnt = WAVE;
        int s_l = 0;
        float w_l[H];
#pragma unroll
        for (int h = 0; h < H; h++) w_l[h] = 0.f;
        if (lane < cnt) {
            int2 pk = cpack[base + lane];
            s_l = pk.x;
            if (GCN) {
                w_l[0] = dinv[s_l] * __int_as_float(pk.y) * di;
            } else {
#pragma unroll
                for (int h = 0; h < H; h++)
                    w_l[h] = __expf(lrelu02(as_[(size_t)s_l * H + h] + adn[h]) - msub[h]);
            }
            if (SM) {
#pragma unroll
                for (int h = 0; h < H; h++) wsum[h] += w_l[h];
            }
        }
        for (int j0 = 0; j0 < cnt; j0 += 2 * G) {
            // group A
            int sA;
            float wA[H];
            uint4 vA[SWEEPS];
            {
                int jj = j0 + g;
                bool pad = (jj >= cnt);
                if (jj > cnt - 1) jj = cnt - 1;
                int ba = jj << 2;
                sA = __builtin_amdgcn_ds_bpermute(ba, s_l);
#pragma unroll
                for (int h = 0; h < H; h++) {
                    float t = __uint_as_float(
                        (unsigned)__builtin_amdgcn_ds_bpermute(ba, (int)__float_as_uint(w_l[h])));
                    wA[h] = pad ? 0.f : t;
                }
                if (act) {
#pragma unroll
                    for (int sw = 0; sw < SWEEPS; sw++) {
                        unsigned voff = (unsigned)sA * ROWB + (sw * SLOTS + slot) * 16;
                        vA[sw] = *(const uint4*)((const char*)hfeat + voff);
                    }
                }
            }
            // group B (uniform predicate)
            bool haveB = (j0 + G < cnt);
            int sB;
            float wB[H];
            uint4 vB[SWEEPS];
            if (haveB) {
                int jj = j0 + G + g;
                bool pad = (jj >= cnt);
                if (jj > cnt - 1) jj = cnt - 1;
                int ba = jj << 2;
                sB = __builtin_amdgcn_ds_bpermute(ba, s_l);
#pragma unroll
                for (int h = 0; h < H; h++) {
                    float t = __uint_as_float(
                        (unsigned)__builtin_amdgcn_ds_bpermute(ba, (int)__float_as_uint(w_l[h])));
                    wB[h] = pad ? 0.f : t;
                }
                if (act) {
#pragma unroll
                    for (int sw = 0; sw < SWEEPS; sw++) {
                        unsigned voff = (unsigned)sB * ROWB + (sw * SLOTS + slot) * 16;
                        vB[sw] = *(const uint4*)((const char*)hfeat + voff);
                    }
                }
            }
            if (act) {
#pragma unroll
                for (int sw = 0; sw < SWEEPS; sw++) {
                    unsigned int va[4] = {vA[sw].x, vA[sw].y, vA[sw].z, vA[sw].w};
#pragma unroll
                    for (int q = 0; q < 4; q++) {
                        float wq = (H == 2) ? (h1q[sw][q] ? wA[1] : wA[0]) : wA[0];
                        accx[sw][q] += wq * bf2f_lo(va[q]);
                        accy[sw][q] += wq * bf2f_hi(va[q]);
                    }
                }
                if (haveB) {
#pragma unroll
                    for (int sw = 0; sw < SWEEPS; sw++) {
                        unsigned int ub[4] = {vB[sw].x, vB[sw].y, vB[sw].z, vB[sw].w};
#pragma unroll
                        for (int q = 0; q < 4; q++) {
                            float wq = (H == 2) ? (h1q[sw][q] ? wB[1] : wB[0]) : wB[0];
                            accx[sw][q] += wq * bf2f_lo(ub[q]);
                            accy[sw][q] += wq * bf2f_hi(ub[q]);
                        }
                    }
                }
            }
        }
    }

    // cross-group channel reduction into lanes [0, SLOTS)
    if (G == 3) {
#pragma unroll
        for (int sw = 0; sw < SWEEPS; sw++)
#pragma unroll
            for (int q = 0; q < 4; q++) {
                int b1a = (lane + SLOTS) << 2, b2a = (lane + 2 * SLOTS) << 2;
                float t1 = __uint_as_float((unsigned)__builtin_amdgcn_ds_bpermute(b1a, (int)__float_as_uint(accx[sw][q])));
                float t2 = __uint_as_float((unsigned)__builtin_amdgcn_ds_bpermute(b2a, (int)__float_as_uint(accx[sw][q])));
                accx[sw][q] += t1 + t2;
                float t3 = __uint_as_float((unsigned)__builtin_amdgcn_ds_bpermute(b1a, (int)__float_as_uint(accy[sw][q])));
                float t4 = __uint_as_float((unsigned)__builtin_amdgcn_ds_bpermute(b2a, (int)__float_as_uint(accy[sw][q])));
                accy[sw][q] += t3 + t4;
            }
    } else if (G == 8) {
#pragma unroll
        for (int st = 4; st >= 1; st >>= 1) {
            int ba = (lane + st * SLOTS) << 2;
#pragma unroll
            for (int sw = 0; sw < SWEEPS; sw++)
#pragma unroll
                for (int q = 0; q < 4; q++) {
                    accx[sw][q] += __uint_as_float((unsigned)__builtin_amdgcn_ds_bpermute(ba, (int)__float_as_uint(accx[sw][q])));
                    accy[sw][q] += __uint_as_float((unsigned)__builtin_amdgcn_ds_bpermute(ba, (int)__float_as_uint(accy[sw][q])));
                }
        }
    }

    float rs[H];
    if (SM) {
#pragma unroll
        for (int h = 0; h < H; h++) {
            float t = wsum[h];
            for (int off = 32; off > 0; off >>= 1) t += __shfl_xor(t, off);
            rs[h] = 1.f / (1.f + t + 1e-16f);  // +1 = self term
        }
    } else {
#pragma unroll
        for (int h = 0; h < H; h++) rs[h] = 1.f;
    }

    if (lane < SLOTS) {
#pragma unroll
        for (int sw = 0; sw < SWEEPS; sw++) {
            float o[8];
#pragma unroll
            for (int q = 0; q < 4; q++) {
                float r = (H == 2) ? (h1q[sw][q] ? rs[1] : rs[0]) : rs[0];
                int c0 = ch0[sw] + 2 * q;
                float b0 = (c0 < HC) ? bias[c0] : 0.f;
                float b1v = (c0 + 1 < HC) ? bias[c0 + 1] : 0.f;
                float o0 = accx[sw][q] * r + b0;
                float o1 = accy[sw][q] * r + b1v;
                if (relu) { o0 = fmaxf(o0, 0.f); o1 = fmaxf(o1, 0.f); }
                if (c0 >= HC) o0 = 0.f;
                if (c0 + 1 >= HC) o1 = 0.f;
                o[2 * q] = o0;
                o[2 * q + 1] = o1;
            }
            if (out_bf) {
                uint4 pk;
                unsigned* pp = (unsigned*)&pk;
#pragma unroll
                for (int q = 0; q < 4; q++)
                    pp[q] = (unsigned)f2bf(o[2 * q]) | ((unsigned)f2bf(o[2 * q + 1]) << 16);
                *(uint4*)((char*)out_bf + (size_t)n * ((size_t)ldo * 2) + (sw * SLOTS + slot) * 16) = pk;
            } else {
#pragma unroll
                for (int half = 0; half < 2; half++) {
                    int c0 = ch0[sw] + half * 4;
                    if (c0 < HC) {
                        float4 f4 = make_float4(o[half * 4], o[half * 4 + 1], o[half * 4 + 2], o[half * 4 + 3]);
                        *(float4*)(out_f + (size_t)n * HC + c0) = f4;
                    }
                }
            }
        }
    }
}

// ==================== helpers for kernel A ====================

__device__ __forceinline__ void cvtw1(const float* __restrict__ W, unsigned short* __restrict__ WT,
                                      int K, int M, int Kp, int i) {
    int m = i / Kp;
    int k = i - m * Kp;
    WT[i] = (k < K) ? f2bf(W[(long long)k * M + m]) : (unsigned short)0;
}

__device__ __forceinline__ void prep1(const float* __restrict__ W, const float* __restrict__ a_src,
                                      const float* __restrict__ a_dst, unsigned short* __restrict__ WT,
                                      int K, int M, int C, int Kp, int H, int b, int lane) {
    int k = b % Kp;
    int th = b / Kp;
    int t = th / H;
    int h = th - t * H;
    size_t orow = (size_t)(M + t * H + h) * Kp;
    if (k >= K) {
        if (lane == 0) WT[orow + k] = 0;
        return;
    }
    const float* a = t ? a_dst : a_src;
    int hoff = h * C;
    const float* wrow = W + (size_t)k * M + hoff;
    float acc = 0.f;
    for (int c = lane; c < C; c += 64) acc += wrow[c] * a[hoff + c];
    for (int off = 32; off > 0; off >>= 1) acc += __shfl_down(acc, off);
    if (lane == 0) WT[orow + k] = f2bf(acc);
}

// ==================== kernel A: count ∪ cvt_w ∪ prep_va ∪ cvt_x ====================

__global__ __launch_bounds__(256) void k_A(
    const int* __restrict__ mol_dst, const int* __restrict__ pro_dst, int* __restrict__ cnt,
    int N_MOL, int E_MOL, int ET, int nb1,
    const float* __restrict__ W1, const float* __restrict__ W2, const float* __restrict__ W3,
    const float* __restrict__ Wp1, const float* __restrict__ Wp2, const float* __restrict__ Wp3,
    unsigned short* __restrict__ wt1, unsigned short* __restrict__ wt2, unsigned short* __restrict__ wt3,
    unsigned short* __restrict__ wtp1, unsigned short* __restrict__ wtp2, unsigned short* __restrict__ wtp3,
    const float* __restrict__ as1, const float* __restrict__ ad1,
    const float* __restrict__ as2, const float* __restrict__ ad2,
    const float* __restrict__ as3, const float* __restrict__ ad3,
    const float* __restrict__ aps2, const float* __restrict__ apd2,
    const float* __restrict__ aps3, const float* __restrict__ apd3,
    const float* __restrict__ mol_x, unsigned short* __restrict__ xb,
    const float* __restrict__ pro_x, unsigned short* __restrict__ xpp,
    long long totM, long long totP) {
    const int nb2 = 730;   // cvt_w: 186792/256
    const int nb3 = 508;   // prep: 2032 units / 4 waves
    int b = blockIdx.x;
    int tid = threadIdx.x;
    if (b < nb1) {
        // count (ILP4)
        int i0 = b * 1024 + tid;
#pragma unroll
        for (int k = 0; k < 4; k++) {
            int e = i0 + k * 256;
            if (e < ET) {
                int d = (e < E_MOL) ? mol_dst[e] : (N_MOL + pro_dst[e - E_MOL]);
                atomicAdd(&cnt[d], 1);
            }
        }
    } else if (b < nb1 + nb2) {
        int idx = (b - nb1) * 256 + tid;
        if (idx < 12480)        cvtw1(W1, wt1, 78, 156, 80, idx);
        else if (idx < 62400)   cvtw1(W2, wt2, 156, 312, 160, idx - 12480);
        else if (idx < 162240)  cvtw1(W3, wt3, 312, 312, 320, idx - 62400);
        else if (idx < 163560)  cvtw1(Wp1, wtp1, 33, 33, 40, idx - 162240);
        else if (idx < 168840)  cvtw1(Wp2, wtp2, 33, 132, 40, idx - 163560);
        else if (idx < 186792)  cvtw1(Wp3, wtp3, 132, 132, 136, idx - 168840);
    } else if (b < nb1 + nb2 + nb3) {
        int unit = (b - nb1 - nb2) * 4 + (tid >> 6);
        int lane = tid & 63;
        if (unit < 320)        prep1(W1, as1, ad1, wt1, 78, 156, 78, 80, 2, unit, lane);
        else if (unit < 960)   prep1(W2, as2, ad2, wt2, 156, 312, 156, 160, 2, unit - 320, lane);
        else if (unit < 1600)  prep1(W3, as3, ad3, wt3, 312, 312, 312, 320, 1, unit - 960, lane);
        else if (unit < 1760)  prep1(Wp2, aps2, apd2, wtp2, 33, 132, 66, 40, 2, unit - 1600, lane);
        else if (unit < 2032)  prep1(Wp3, aps3, apd3, wtp3, 132, 132, 132, 136, 1, unit - 1760, lane);
    } else {
        long long i0 = (long long)(b - nb1 - nb2 - nb3) * 1024 + tid;
#pragma unroll
        for (int k = 0; k < 4; k++) {
            long long idx = i0 + k * 256;
            if (idx < totM) {
                int n = (int)(idx / 80);
                int kk = (int)(idx - (long long)n * 80);
                xb[idx] = (kk < 78) ? f2bf(mol_x[(long long)n * 78 + kk]) : (unsigned short)0;
            } else if (idx < totM + totP) {
                long long i2 = idx - totM;
                int n = (int)(i2 / 40);
                int kk = (int)(i2 - (long long)n * 40);
                xpp[i2] = (kk < 33) ? f2bf(pro_x[(long long)n * 33 + kk]) : (unsigned short)0;
            }
        }
    }
}

// ==================== scans ====================

__global__ __launch_bounds__(256) void k_scan1(const int* __restrict__ cnt, int* __restrict__ incl,
                                               int* __restrict__ bsums, int n) {
    __shared__ int sm[256];
    int i = blockIdx.x * 256 + threadIdx.x;
    int v = (i < n) ? cnt[i] : 0;
    sm[threadIdx.x] = v;
    __syncthreads();
    for (int off = 1; off < 256; off <<= 1) {
        int t = (threadIdx.x >= off) ? sm[threadIdx.x - off] : 0;
        __syncthreads();
        sm[threadIdx.x] += t;
        __syncthreads();
    }
    if (i < n) incl[i] = sm[threadIdx.x];
    if (threadIdx.x == 255) bsums[blockIdx.x] = sm[255];
}

__global__ __launch_bounds__(1024) void k_scan2(int* __restrict__ bsums, int nb) {
    __shared__ int sm[1024];
    int v = (threadIdx.x < nb) ? bsums[threadIdx.x] : 0;
    sm[threadIdx.x] = v;
    __syncthreads();
    for (int off = 1; off < 1024; off <<= 1) {
        int t = (threadIdx.x >= off) ? sm[threadIdx.x - off] : 0;
        __syncthreads();
        sm[threadIdx.x] += t;
        __syncthreads();
    }
    if (threadIdx.x < nb) bsums[threadIdx.x] = sm[threadIdx.x] - v;  // exclusive
}

__global__ __launch_bounds__(256) void k_scan3_all(const int* __restrict__ incl, const int* __restrict__ cnt,
                                                   const int* __restrict__ boff,
                                                   int* __restrict__ mol_rowp, int* __restrict__ pro_rowp,
                                                   int* __restrict__ cur,
                                                   int N_MOL, int N_PRO, int E_MOL, int E_PRO) {
    int i = blockIdx.x * 256 + threadIdx.x;
    int NT = N_MOL + N_PRO;
    if (i < NT) {
        int ex = incl[i] - cnt[i] + boff[blockIdx.x];
        cur[i] = ex;
        if (i < N_MOL) mol_rowp[i] = ex;
        else pro_rowp[i - N_MOL] = ex - E_MOL;  // pro rowp is local
    }
    if (i == 0) {
        mol_rowp[N_MOL] = E_MOL;
        pro_rowp[N_PRO] = E_PRO;
    }
}

// ==================== kernel B: scatter ∪ GEMM ∪ GEMM (nbs may be 0) ====================

__global__ __launch_bounds__(256) void k_B(
    const int* __restrict__ msrc, const int* __restrict__ mdst,
    const int* __restrict__ psrc, const int* __restrict__ pdst,
    const float* __restrict__ pw, int* __restrict__ cur, int2* __restrict__ cpack,
    int N_MOL, int E_MOL, int ET, int nbs,
    const unsigned short* __restrict__ A1, const unsigned short* __restrict__ B1,
    unsigned short* __restrict__ C1, float* __restrict__ as1o, float* __restrict__ ad1o,
    int N1, int Kp1, int M1, int Mext1, int Mp1, int H1, int g1x, int nb1,
    const unsigned short* __restrict__ A2, const unsigned short* __restrict__ B2,
    unsigned short* __restrict__ C2, float* __restrict__ as2o, float* __restrict__ ad2o,
    int N2, int Kp2, int M2, int Mext2, int Mp2, int H2, int g2x) {
    int b = blockIdx.x;
    if (b < nbs) {
        int e = b * 256 + threadIdx.x;
        if (e < ET) {
            int s, d;
            int wbits = 0;
            if (e >= E_MOL) {
                int ep = e - E_MOL;
                s = psrc[ep];
                d = N_MOL + pdst[ep];
                wbits = __float_as_int(pw[ep]);
            } else {
                s = msrc[e];
                d = mdst[e];
            }
            int pos = atomicAdd(&cur[d], 1);
            int2 pk;
            pk.x = s;
            pk.y = wbits;
            cpack[pos] = pk;
        }
    } else if (b < nbs + nb1) {
        int bb = b - nbs;
        gemm_body(A1, B1, C1, as1o, ad1o, N1, Kp1, M1, Mext1, Mp1, H1, bb % g1x, bb / g1x);
    } else {
        int bb = b - nbs - nb1;
        gemm_body(A2, B2, C2, as2o, ad2o, N2, Kp2, M2, Mext2, Mp2, H2, bb % g2x, bb / g2x);
    }
}

// ==================== deg/dinv (node-parallel, no atomics) ====================

__global__ __launch_bounds__(256) void k_deg(const int* __restrict__ rowp, const int2* __restrict__ cpack,
                                             float* __restrict__ dinv, int N) {
    int n = blockIdx.x * 256 + threadIdx.x;
    if (n < N) {
        int b = rowp[n], e = rowp[n + 1];
        float s = 0.f;
        for (int p = b; p < e; p++) s += __int_as_float(cpack[p].y);
        dinv[n] = rsqrtf(s + 1.0f);
    }
}

// ==================== fused agg pairs ====================

// F1: mol conv1 (GAT 156, 20 slots) ∪ pro gcn (33, 5 slots, G=8)
__global__ __launch_bounds__(NPB * 64) void k_fuse1(
    const unsigned short* __restrict__ hb, const float* __restrict__ asm_, const float* __restrict__ adm_,
    const int* __restrict__ mrowp, const int2* __restrict__ mcp, const float* __restrict__ b1,
    unsigned short* __restrict__ xb, int Nm,
    const unsigned short* __restrict__ hbp, const float* __restrict__ dinv,
    const int* __restrict__ prowp, const int2* __restrict__ pcp, const float* __restrict__ bp1,
    unsigned short* __restrict__ xpp, int Np, int nb1) {
    int wave = threadIdx.x >> 6, lane = threadIdx.x & 63;
    int b = blockIdx.x;
    if (b < nb1) {
        int n = b * NPB + wave;
        if (n < Nm)
            agg_body<20, 3, 2, true, 1, false>(hb, asm_, adm_, nullptr, mrowp, mcp, b1,
                                               nullptr, xb, 156, 160, 1, n, lane);
    } else {
        int n = (b - nb1) * NPB + wave;
        if (n < Np)
            agg_body<5, 8, 1, false, 1, true>(hbp, nullptr, nullptr, dinv, prowp, pcp, bp1,
                                              nullptr, xpp, 33, 40, 1, n, lane);
    }
}

// F3: mol conv2 (GAT 312, 20 slots x 2 sweeps) ∪ pro conv2 (GAT 132, 17 slots)
__global__ __launch_bounds__(NPB * 64) void k_fuse3(
    const unsigned short* __restrict__ hb, const float* __restrict__ asm_, const float* __restrict__ adm_,
    const int* __restrict__ mrowp, const int2* __restrict__ mcp, const float* __restrict__ b2,
    unsigned short* __restrict__ xb, int Nm,
    const unsigned short* __restrict__ hbp, const float* __restrict__ asp_, const float* __restrict__ adp_,
    const int* __restrict__ prowp, const int2* __restrict__ pcp, const float* __restrict__ bp2,
    unsigned short* __restrict__ xpp, int Np, int nb1) {
    int wave = threadIdx.x >> 6, lane = threadIdx.x & 63;
    int b = blockIdx.x;
    if (b < nb1) {
        int n = b * NPB + wave;
        if (n < Nm)
            agg_body<20, 3, 2, true, 2, false>(hb, asm_, adm_, nullptr, mrowp, mcp, b2,
                                               nullptr, xb, 312, 320, 1, n, lane);
    } else {
        int n = (b - nb1) * NPB + wave;
        if (n < Np)
            agg_body<17, 3, 2, true, 1, false>(hbp, asp_, adp_, nullptr, prowp, pcp, bp2,
                                               nullptr, xpp, 132, 136, 1, n, lane);
    }
}

// F5: mol conv3 (GAT 312 H=1, fp32 out, no relu) ∪ pro conv3 (GAT 132 H=1, fp32 out, relu)
__global__ __launch_bounds__(NPB * 64) void k_fuse5(
    const unsigned short* __restrict__ hb, const float* __restrict__ asm_, const float* __restrict__ adm_,
    const int* __restrict__ mrowp, const int2* __restrict__ mcp, const float* __restrict__ b3,
    float* __restrict__ out_mol, int Nm,
    const unsigned short* __restrict__ hbp, const float* __restrict__ asp_, const float* __restrict__ adp_,
    const int* __restrict__ prowp, const int2* __restrict__ pcp, const float* __restrict__ bp3,
    float* __restrict__ out_pro, int Np, int nb1) {
    int wave = threadIdx.x >> 6, lane = threadIdx.x & 63;
    int b = blockIdx.x;
    if (b < nb1) {
        int n = b * NPB + wave;
        if (n < Nm)
            agg_body<20, 3, 1, true, 2, false>(hb, asm_, adm_, nullptr, mrowp, mcp, b3,
                                               out_mol, nullptr, 312, 320, 0, n, lane);
    } else {
        int n = (b - nb1) * NPB + wave;
        if (n < Np)
            agg_body<17, 3, 1, true, 1, false>(hbp, asp_, adp_, nullptr, prowp, pcp, bp3,
                                               out_pro, nullptr, 132, 136, 1, n, lane);
    }
}

// ==================== launch ====================

extern "C" void kernel_launch(void* const* d_in, const int* in_sizes, int n_in,
                              void* d_out, int out_size, void* d_ws, size_t ws_size,
                              hipStream_t stream) {
    const int N_MOL = in_sizes[0] / 78;
    const int E_MOL = in_sizes[1] / 2;
    const int N_PRO = in_sizes[2] / 33;
    const int E_PRO = in_sizes[3] / 2;
    const int NT = N_MOL + N_PRO;
    const int ET = E_MOL + E_PRO;

    const float* mol_x = (const float*)d_in[0];
    const int* mol_ei = (const int*)d_in[1];
    const float* pro_x = (const float*)d_in[2];
    const int* pro_ei = (const int*)d_in[3];
    const float* pro_ew = (const float*)d_in[4];
    const float *W1 = (const float*)d_in[5], *as1 = (const float*)d_in[6], *ad1 = (const float*)d_in[7],
                *b1 = (const float*)d_in[8];
    const float *W2 = (const float*)d_in[9], *as2 = (const float*)d_in[10], *ad2 = (const float*)d_in[11],
                *b2 = (const float*)d_in[12];
    const float *W3 = (const float*)d_in[13], *as3 = (const float*)d_in[14], *ad3 = (const float*)d_in[15],
                *b3 = (const float*)d_in[16];
    const float *Wp1 = (const float*)d_in[17], *bp1 = (const float*)d_in[18];
    const float *Wp2 = (const float*)d_in[19], *aps2 = (const float*)d_in[20], *apd2 = (const float*)d_in[21],
                *bp2 = (const float*)d_in[22];
    const float *Wp3 = (const float*)d_in[23], *aps3 = (const float*)d_in[24], *apd3 = (const float*)d_in[25],
                *bp3 = (const float*)d_in[26];

    float* out_mol = (float*)d_out;
    float* out_pro = (float*)d_out + (size_t)N_MOL * 312;

    char* p = (char*)d_ws;
    auto alloc = [&](size_t bytes) -> void* {
        void* r = (void*)p;
        p += (bytes + 255) & ~(size_t)255;
        return r;
    };
    int* cnt_all  = (int*)alloc((size_t)NT * 4);
    int* incl     = (int*)alloc((size_t)NT * 4);
    int* cur_all  = (int*)alloc((size_t)NT * 4);
    int* bsums    = (int*)alloc(1024 * 4);
    int* mol_rowp = (int*)alloc((size_t)(N_MOL + 1) * 4);
    int* pro_rowp = (int*)alloc((size_t)(N_PRO + 1) * 4);
    int2* cpack   = (int2*)alloc((size_t)ET * 8);
    float* dinv   = (float*)alloc((size_t)N_PRO * 4);
    float* asb_m = (float*)alloc((size_t)N_MOL * 2 * 4);
    float* adb_m = (float*)alloc((size_t)N_MOL * 2 * 4);
    float* asb_p = (float*)alloc((size_t)N_PRO * 2 * 4);
    float* adb_p = (float*)alloc((size_t)N_PRO * 2 * 4);
    unsigned short* hb  = (unsigned short*)alloc((size_t)N_MOL * 320 * 2);  // mol GEMM out
    unsigned short* xb  = (unsigned short*)alloc((size_t)N_MOL * 320 * 2);  // mol activations
    unsigned short* hbp = (unsigned short*)alloc((size_t)N_PRO * 136 * 2);  // pro GEMM out
    unsigned short* xpp = (unsigned short*)alloc((size_t)N_PRO * 136 * 2);  // pro activations
    unsigned short* wt1 = (unsigned short*)alloc((size_t)160 * 80 * 2);
    unsigned short* wt2 = (unsigned short*)alloc((size_t)320 * 160 * 2);
    unsigned short* wt3 = (unsigned short*)alloc((size_t)320 * 320 * 2);
    unsigned short* wtp1 = (unsigned short*)alloc((size_t)40 * 40 * 2);
    unsigned short* wtp2 = (unsigned short*)alloc((size_t)136 * 40 * 2);
    unsigned short* wtp3 = (unsigned short*)alloc((size_t)136 * 136 * 2);
    (void)ws_size;

    int2* mol_cp = cpack;            // mol edges at [0, E_MOL)
    int2* pro_cp = cpack + E_MOL;    // pro edges at [E_MOL, ET), local pointers

    const int* mol_src = mol_ei;
    const int* mol_dst = mol_ei + E_MOL;
    const int* pro_src = pro_ei;
    const int* pro_dst = pro_ei + E_PRO;

    const long long totM = (long long)N_MOL * 80;
    const long long totP = (long long)N_PRO * 40;

    // ---- A: count ∪ cvt_w ∪ prep_va ∪ cvt_x ----
    hipMemsetAsync(cnt_all, 0, (size_t)NT * 4, stream);
    int nbCnt = (ET + 1023) / 1024;
    int nbCvx = (int)((totM + totP + 1023) / 1024);
    int gridA = nbCnt + 730 + 508 + nbCvx;
    k_A<<<gridA, 256, 0, stream>>>(mol_dst, pro_dst, cnt_all, N_MOL, E_MOL, ET, nbCnt,
                                   W1, W2, W3, Wp1, Wp2, Wp3, wt1, wt2, wt3, wtp1, wtp2, wtp3,
                                   as1, ad1, as2, ad2, as3, ad3, aps2, apd2, aps3, apd3,
                                   mol_x, xb, pro_x, xpp, totM, totP);

    // ---- scans ----
    int nbT = (NT + 255) / 256;
    k_scan1<<<nbT, 256, 0, stream>>>(cnt_all, incl, bsums, NT);
    k_scan2<<<1, 1024, 0, stream>>>(bsums, nbT);
    k_scan3_all<<<nbT, 256, 0, stream>>>(incl, cnt_all, bsums, mol_rowp, pro_rowp, cur_all,
                                         N_MOL, N_PRO, E_MOL, E_PRO);

    int gyM = (N_MOL + TBM - 1) / TBM;   // 391
    int gyP = (N_PRO + TBM - 1) / TBM;   // 782

    // ---- B: scatter ∪ mol gemm1 (78->156+4) ∪ pro gemm1 (33->33) ----
    {
        int nbs = (ET + 255) / 256;
        int g1x = (160 + TBN - 1) / TBN;  // Mext=160 -> 2
        int nb1 = g1x * gyM;
        int g2x = 1;                       // Mext=33
        int nb2 = g2x * gyP;
        k_B<<<nbs + nb1 + nb2, 256, 0, stream>>>(
            mol_src, mol_dst, pro_src, pro_dst, pro_ew, cur_all, cpack, N_MOL, E_MOL, ET, nbs,
            xb, wt1, hb, asb_m, adb_m, N_MOL, 80, 156, 160, 160, 2, g1x, nb1,
            xpp, wtp1, hbp, nullptr, nullptr, N_PRO, 40, 33, 33, 40, 0, g2x);
    }

    k_deg<<<(N_PRO + 255) / 256, 256, 0, stream>>>(pro_rowp, pro_cp, dinv, N_PRO);

    // ---- F1: mol conv1 agg ∪ pro gcn agg ----
    {
        int nb1 = (N_MOL + NPB - 1) / NPB;
        int nb2 = (N_PRO + NPB - 1) / NPB;
        k_fuse1<<<nb1 + nb2, NPB * 64, 0, stream>>>(hb, asb_m, adb_m, mol_rowp, mol_cp, b1, xb, N_MOL,
                                                    hbp, dinv, pro_rowp, pro_cp, bp1, xpp, N_PRO, nb1);
    }

    // ---- F2: mol gemm2 (156->312+4) ∪ pro gemm2 (33->132+4) ----
    {
        int g1x = (316 + TBN - 1) / TBN;  // 3
        int nb1 = g1x * gyM;
        int g2x = (136 + TBN - 1) / TBN;  // 2
        int nb2 = g2x * gyP;
        k_B<<<nb1 + nb2, 256, 0, stream>>>(
            nullptr, nullptr, nullptr, nullptr, nullptr, nullptr, nullptr, N_MOL, E_MOL, ET, 0,
            xb, wt2, hb, asb_m, adb_m, N_MOL, 160, 312, 316, 320, 2, g1x, nb1,
            xpp, wtp2, hbp, asb_p, adb_p, N_PRO, 40, 132, 136, 136, 2, g2x);
    }

    // ---- F3: mol conv2 agg ∪ pro conv2 agg ----
    {
        int nb1 = (N_MOL + NPB - 1) / NPB;
        int nb2 = (N_PRO + NPB - 1) / NPB;
        k_fuse3<<<nb1 + nb2, NPB * 64, 0, stream>>>(hb, asb_m, adb_m, mol_rowp, mol_cp, b2, xb, N_MOL,
                                                    hbp, asb_p, adb_p, pro_rowp, pro_cp, bp2, xpp, N_PRO, nb1);
    }

    // ---- F4: mol gemm3 (312->312+2) ∪ pro gemm3 (132->132+2) ----
    {
        int g1x = (314 + TBN - 1) / TBN;  // 3
        int nb1 = g1x * gyM;
        int g2x = (134 + TBN - 1) / TBN;  // 2
        int nb2 = g2x * gyP;
        k_B<<<nb1 + nb2, 256, 0, stream>>>(
            nullptr, nullptr, nullptr, nullptr, nullptr, nullptr, nullptr, N_MOL, E_MOL, ET, 0,
            xb, wt3, hb, asb_m, adb_m, N_MOL, 320, 312, 314, 320, 1, g1x, nb1,
            xpp, wtp3, hbp, asb_p, adb_p, N_PRO, 136, 132, 134, 136, 1, g2x);
    }

    // ---- F5: mol conv3 agg (fp32, no relu) ∪ pro conv3 agg (fp32, relu) ----
    {
        int nb1 = (N_MOL + NPB - 1) / NPB;
        int nb2 = (N_PRO + NPB - 1) / NPB;
        k_fuse5<<<nb1 + nb2, NPB * 64, 0, stream>>>(hb, asb_m, adb_m, mol_rowp, mol_cp, b3, out_mol, N_MOL,
                                                    hbp, asb_p, adb_p, pro_rowp, pro_cp, bp3, out_pro, N_PRO, nb1);
    }
}